// Round 10
// baseline (765.986 us; speedup 1.0000x reference)
//
#include <hip/hip_runtime.h>
#include <hip/hip_bf16.h>

// MultiHeadAttention fused pipeline for MI355X (gfx950).
// Outputs: [0] out (2*2048*1024 f32), [1] attn (2*16*2048*2048 f32), concatenated in d_out.
// ws layout: [flag:256B][qh 8MB][kh 8MB][vt 8MB][ao 8MB][wt 4x2MB][mbits 1MB][S16 268MB] = ~311MB.
// Falls back to the round-9 fused k_attn if ws_size is smaller.

typedef __attribute__((ext_vector_type(8))) short bf16x8;
typedef __attribute__((ext_vector_type(8))) _Float16 f16x8;
typedef __attribute__((ext_vector_type(4))) float f32x4;
typedef __attribute__((ext_vector_type(4))) int i32x4;
typedef __attribute__((ext_vector_type(4))) _Float16 f16x4;
typedef unsigned short u16;

#define NB 2
#define QL 2048
#define KL 2048
#define CH 1024
#define NH 16
#define HD 64
#define SH_STRIDE 2600   // f16 elems; keeps LDS ~85KB -> exactly 1 block/CU (clean-write regime)

__device__ __forceinline__ u16 f2bf(float f){
  unsigned u = __float_as_uint(f);
  u += 0x7fffu + ((u >> 16) & 1u);   // RNE
  return (u16)(u >> 16);
}
__device__ __forceinline__ u16 f2h(float f){
  _Float16 h = (_Float16)f;
  return *(u16*)&h;
}

// ---------------- mask dtype detector: int32 0/1 vs packed bool bytes ----------------
__global__ void k_detect(const unsigned int* __restrict__ m, int* __restrict__ flag){
  unsigned v = m[threadIdx.x];
  unsigned long long b = __ballot(v > 1u);   // bool-packed words look like 0x00010100 etc.
  __shared__ int r[4];
  if ((threadIdx.x & 63) == 0) r[threadIdx.x >> 6] = (b != 0ULL);
  __syncthreads();
  if (threadIdx.x == 0) *flag = (r[0] | r[1] | r[2] | r[3]);
}

// ---------------- mask -> 1 bit/elem (1MB total; stays L2/L3-resident) ----------------
__global__ __launch_bounds__(256) void k_maskpack(const void* __restrict__ maskp, const int* __restrict__ flag,
                                                  unsigned* __restrict__ mbits){
  const int idx = blockIdx.x*256 + threadIdx.x;   // 262144 words, 32 mask elems each
  unsigned out = 0;
  if (*flag){
    const unsigned* m8 = (const unsigned*)maskp + (size_t)idx*8;   // 32 bool bytes
    #pragma unroll
    for (int j=0;j<8;++j){
      unsigned wv = m8[j];
      out |= ((wv & 1u) | ((wv>>7)&2u) | ((wv>>14)&4u) | ((wv>>21)&8u)) << (4*j);
    }
  } else {
    const i32x4* m32 = (const i32x4*)maskp + (size_t)idx*8;        // 32 ints
    #pragma unroll
    for (int j=0;j<8;++j){
      i32x4 v = m32[j];
      out |= (unsigned)((v[0]&1) | ((v[1]&1)<<1) | ((v[2]&1)<<2) | ((v[3]&1)<<3)) << (4*j);
    }
  }
  mbits[idx] = out;
}

// ---------------- weight transpose + bf16 convert: W[in][out] -> Wt[out][in] ----------------
__global__ __launch_bounds__(256) void k_transpose(const float* __restrict__ Wq, const float* __restrict__ Wk,
                                                   const float* __restrict__ Wv, const float* __restrict__ Wo,
                                                   u16* __restrict__ wt){
  const float* src = blockIdx.z==0 ? Wq : blockIdx.z==1 ? Wk : blockIdx.z==2 ? Wv : Wo;
  u16* dst = wt + (size_t)blockIdx.z * CH * CH;
  __shared__ float t[32][33];
  const int x = blockIdx.x*32, y = blockIdx.y*32;
  const int tx = threadIdx.x & 31, ty = threadIdx.x >> 5;
  #pragma unroll
  for (int j=0;j<32;j+=8) t[ty+j][tx] = src[(size_t)(y+ty+j)*CH + x + tx];
  __syncthreads();
  #pragma unroll
  for (int j=0;j<32;j+=8) dst[(size_t)(x+ty+j)*CH + y + tx] = f2bf(t[tx][ty+j]);
}

// ---------------- merged QKV projection GEMM: C(4096xCH) = A @ Wt^T + bias ----------------
// z=0: qh ([b,h,q,64] bf16, scaled by 1/32); z=1: kh (same); z=2: vt ([b,h,64,K] f16)
__global__ __launch_bounds__(256) void k_gemm_qkv(const float* __restrict__ q, const float* __restrict__ k,
                                                  const float* __restrict__ v, const u16* __restrict__ wt,
                                                  const float* __restrict__ bq, const float* __restrict__ bk,
                                                  const float* __restrict__ bv,
                                                  u16* __restrict__ qh, u16* __restrict__ kh, u16* __restrict__ vt){
  const int z = blockIdx.z;
  const float* A = z==0 ? q : z==1 ? k : v;
  const u16* Bt = wt + (size_t)z*CH*CH;
  const float* bias = z==0 ? bq : z==1 ? bk : bv;
  u16* Cp = z==0 ? qh : z==1 ? kh : vt;
  const float scale = (z==0) ? 0.03125f : 1.0f;

  __shared__ u16 As[64][72];
  __shared__ u16 Bs[64][72];
  const int m0 = blockIdx.y*64, n0 = blockIdx.x*64;
  const int tid = threadIdx.x, lane = tid & 63, w = tid >> 6;
  const int wm = w >> 1, wn = w & 1;
  const int lr = lane & 15, lg = lane >> 4;
  f32x4 acc[2][2] = {};
  for (int k0 = 0; k0 < CH; k0 += 64){
    #pragma unroll
    for (int j=0;j<4;++j){
      int idx = tid + 256*j, r = idx >> 4, c = (idx & 15)*4;
      float4 vv = *(const float4*)&A[(size_t)(m0+r)*CH + k0 + c];
      ushort4 s; s.x=f2bf(vv.x); s.y=f2bf(vv.y); s.z=f2bf(vv.z); s.w=f2bf(vv.w);
      *(ushort4*)&As[r][c] = s;
    }
    #pragma unroll
    for (int j=0;j<2;++j){
      int idx = tid + 256*j, r = idx >> 3, c = (idx & 7)*8;
      *(uint4*)&Bs[r][c] = *(const uint4*)&Bt[(size_t)(n0+r)*CH + k0 + c];
    }
    __syncthreads();
    #pragma unroll
    for (int kk=0; kk<2; ++kk){
      bf16x8 a0 = *(const bf16x8*)&As[wm*32      + lr][kk*32 + lg*8];
      bf16x8 a1 = *(const bf16x8*)&As[wm*32 + 16 + lr][kk*32 + lg*8];
      bf16x8 b0 = *(const bf16x8*)&Bs[wn*32      + lr][kk*32 + lg*8];
      bf16x8 b1 = *(const bf16x8*)&Bs[wn*32 + 16 + lr][kk*32 + lg*8];
      acc[0][0] = __builtin_amdgcn_mfma_f32_16x16x32_bf16(a0,b0,acc[0][0],0,0,0);
      acc[0][1] = __builtin_amdgcn_mfma_f32_16x16x32_bf16(a0,b1,acc[0][1],0,0,0);
      acc[1][0] = __builtin_amdgcn_mfma_f32_16x16x32_bf16(a1,b0,acc[1][0],0,0,0);
      acc[1][1] = __builtin_amdgcn_mfma_f32_16x16x32_bf16(a1,b1,acc[1][1],0,0,0);
    }
    __syncthreads();
  }
  #pragma unroll
  for (int fi=0;fi<2;++fi)
  #pragma unroll
  for (int fj=0;fj<2;++fj)
  #pragma unroll
  for (int r=0;r<4;++r){
    int row = m0 + wm*32 + fi*16 + lg*4 + r;   // C/D: col=lane&15, row=(lane>>4)*4+reg
    int col = n0 + wn*32 + fj*16 + lr;
    float val = (acc[fi][fj][r] + bias[col]) * scale;
    int bb = row >> 11, ll = row & 2047, hh = col >> 6, dd = col & 63;
    if (z < 2){
      Cp[(((size_t)(bb*NH+hh)*QL + ll) << 6) + dd] = f2bf(val);
    } else {
      Cp[(((size_t)(bb*NH+hh) << 6) + dd)*KL + ll] = f2h(val);   // vt in f16 for f16-MFMA PV
    }
  }
}

// ---------------- final projection GEMM: out = ao @ Wo^T + bo (f32 out) ----------------
__global__ __launch_bounds__(256) void k_gemm_out(const u16* __restrict__ Ap, const u16* __restrict__ Bt,
                                                  const float* __restrict__ bias, float* __restrict__ Cp){
  __shared__ u16 As[64][72];
  __shared__ u16 Bs[64][72];
  const int m0 = blockIdx.y*64, n0 = blockIdx.x*64;
  const int tid = threadIdx.x, lane = tid & 63, w = tid >> 6;
  const int wm = w >> 1, wn = w & 1;
  const int lr = lane & 15, lg = lane >> 4;
  f32x4 acc[2][2] = {};
  for (int k0 = 0; k0 < CH; k0 += 64){
    #pragma unroll
    for (int j=0;j<2;++j){
      int idx = tid + 256*j, r = idx >> 3, c = (idx & 7)*8;
      *(uint4*)&As[r][c] = *(const uint4*)&Ap[(size_t)(m0+r)*CH + k0 + c];
      *(uint4*)&Bs[r][c] = *(const uint4*)&Bt[(size_t)(n0+r)*CH + k0 + c];
    }
    __syncthreads();
    #pragma unroll
    for (int kk=0; kk<2; ++kk){
      bf16x8 a0 = *(const bf16x8*)&As[wm*32      + lr][kk*32 + lg*8];
      bf16x8 a1 = *(const bf16x8*)&As[wm*32 + 16 + lr][kk*32 + lg*8];
      bf16x8 b0 = *(const bf16x8*)&Bs[wn*32      + lr][kk*32 + lg*8];
      bf16x8 b1 = *(const bf16x8*)&Bs[wn*32 + 16 + lr][kk*32 + lg*8];
      acc[0][0] = __builtin_amdgcn_mfma_f32_16x16x32_bf16(a0,b0,acc[0][0],0,0,0);
      acc[0][1] = __builtin_amdgcn_mfma_f32_16x16x32_bf16(a0,b1,acc[0][1],0,0,0);
      acc[1][0] = __builtin_amdgcn_mfma_f32_16x16x32_bf16(a1,b0,acc[1][0],0,0,0);
      acc[1][1] = __builtin_amdgcn_mfma_f32_16x16x32_bf16(a1,b1,acc[1][1],0,0,0);
    }
    __syncthreads();
  }
  #pragma unroll
  for (int fi=0;fi<2;++fi)
  #pragma unroll
  for (int fj=0;fj<2;++fj)
  #pragma unroll
  for (int r=0;r<4;++r){
    int row = m0 + wm*32 + fi*16 + lg*4 + r;
    int col = n0 + wn*32 + fj*16 + lr;
    Cp[(size_t)row*CH + col] = acc[fi][fj][r] + bias[col];
  }
}

// ---------------- split kernel 1: QK^T + bias + mask + exp + rowsum -> normalized S16 (f16) ----------------
// 1 block/CU (Sh ~83KB), 16 waves; wave w owns cols [w*128, w*128+128); read-dominated stream.
__global__ __launch_bounds__(1024, 1) void k_qk(const u16* __restrict__ qh, const u16* __restrict__ kh,
                                                const float* __restrict__ bias,
                                                const unsigned* __restrict__ mbits,
                                                _Float16* __restrict__ S16){
  __shared__ _Float16 Sh[16][SH_STRIDE];   // 83.2 KB
  __shared__ float wsum[16][16];
  __shared__ float inv_l[16];
  const int qt = blockIdx.x, h = blockIdx.y, b = blockIdx.z;
  const int q0 = qt*16, bh = b*NH + h;
  const int tid = threadIdx.x, lane = tid & 63, w = tid >> 6;  // w 0..15
  const int lr = lane & 15, lg = lane >> 4;
  const u16* qb = qh + ((size_t)bh*QL + q0)*HD;
  const bf16x8 qf0 = *(const bf16x8*)&qb[lr*HD +      lg*8];
  const bf16x8 qf1 = *(const bf16x8*)&qb[lr*HD + 32 + lg*8];
  const float* bb = bias + ((size_t)bh*QL + q0)*KL;
  const u16* khb = kh + (size_t)bh*KL*HD;
  const int c0 = w*128;

  // hoisted bias + mask-bit loads (deep fetch pipeline)
  f32x4 bi[8];
  unsigned mwd[8];
  #pragma unroll
  for (int ct=0; ct<8; ++ct){
    const int cb = c0 + ct*16 + lg*4;
    bi[ct] = *(const f32x4*)&bb[(size_t)lr*KL + cb];
    mwd[ct] = mbits[((size_t)b*QL + q0 + lr)*(KL/32) + (cb>>5)];
  }

  float ps = 0.f;
  #pragma unroll
  for (int ct=0; ct<8; ++ct){
    const int cb = c0 + ct*16 + lg*4;
    f32x4 acc = bi[ct];
    const int kcol = c0 + ct*16 + lr;
    bf16x8 kf0 = *(const bf16x8*)&khb[(size_t)kcol*HD +      lg*8];
    bf16x8 kf1 = *(const bf16x8*)&khb[(size_t)kcol*HD + 32 + lg*8];
    acc = __builtin_amdgcn_mfma_f32_16x16x32_bf16(kf0, qf0, acc, 0,0,0);   // D = S^T frag
    acc = __builtin_amdgcn_mfma_f32_16x16x32_bf16(kf1, qf1, acc, 0,0,0);
    const unsigned msel = (mwd[ct] >> (cb & 31)) & 0xFu;
    f16x4 sv;
    #pragma unroll
    for (int r=0;r<4;++r){
      float e = ((msel >> r) & 1u) ? 0.f : __expf(acc[r]);   // logits bounded: no max-sub
      sv[r] = (_Float16)e;
      ps += e;
    }
    *(f16x4*)&Sh[lr][cb] = sv;
  }
  ps += __shfl_xor(ps, 16);
  ps += __shfl_xor(ps, 32);
  if (lane < 16) wsum[w][lr] = ps;
  __syncthreads();
  if (tid < 16){
    float s = 0.f;
    #pragma unroll
    for (int ww=0; ww<16; ++ww) s += wsum[ww][tid];
    inv_l[tid] = 1.f / s;
  }
  __syncthreads();

  // burst-write NORMALIZED S16: wave w owns row w; 1KB contiguous per instruction
  _Float16* sg = S16 + ((size_t)bh*QL + q0 + w)*KL;
  const float ivw = inv_l[w];
  #pragma unroll
  for (int ch=0; ch<4; ++ch){
    f16x8 hv = *(const f16x8*)&Sh[w][ch*512 + lane*8];
    f16x8 ov;
    #pragma unroll
    for (int j=0;j<8;++j) ov[j] = (_Float16)((float)hv[j] * ivw);
    *(f16x8*)&sg[ch*512 + lane*8] = ov;
  }
}

// ---------------- split kernel 2: S16 -> f32 attn stream + PV + ao; write-dominated, barrier-free core ----------------
// 1 block/CU enforced via LDS pad; waves 0-7 PV (f16 MFMA, dual 8-deep batches), waves 8-15 attn stream.
__global__ __launch_bounds__(1024, 1) void k_pv(const _Float16* __restrict__ S16, const _Float16* __restrict__ vt,
                                                float* __restrict__ attn, u16* __restrict__ ao){
  __shared__ float osum[8][16][17];       // 8.7 KB
  __shared__ float pad[18500];            // +74 KB -> 82.7 KB total: forces 1 block/CU
  const int qt = blockIdx.x, h = blockIdx.y, b = blockIdx.z;
  const int q0 = qt*16, bh = b*NH + h;
  const int tid = threadIdx.x, lane = tid & 63, w = tid >> 6;
  const int lr = lane & 15, lg = lane >> 4;
  ((volatile float*)pad)[tid] = 0.f;      // keep the LDS allocation live
  const _Float16* sb = S16 + ((size_t)bh*QL + q0)*KL;

  if (w < 8){
    // PV: d-strip (w&3)*16, K-half (w>>2)*1024; S16 and V both global, 8-deep batches
    const int d0 = (w & 3)*16, kb0 = (w >> 2)*1024;
    const _Float16* vtb = vt + (size_t)bh*HD*KL;
    f32x4 oacc = {};
    #pragma unroll
    for (int kb=0; kb<4; ++kb){
      f16x8 vf[8], af[8];
      #pragma unroll
      for (int i=0;i<8;++i){
        vf[i] = *(const f16x8*)&vtb[(size_t)(d0+lr)*KL + kb0 + kb*256 + i*32 + lg*8];
        af[i] = *(const f16x8*)&sb[(size_t)lr*KL + kb0 + kb*256 + i*32 + lg*8];
      }
      #pragma unroll
      for (int i=0;i<8;++i)
        oacc = __builtin_amdgcn_mfma_f32_16x16x32_f16(af[i], vf[i], oacc, 0,0,0);
    }
    #pragma unroll
    for (int r=0;r<4;++r) osum[w][lg*4+r][lr] = oacc[r];
  } else {
    // attn stream: wave owns 2 rows; read f16x4 (8B/lane), store f32x4 (16B/lane = 1KB contiguous)
    float* ob = attn + ((size_t)bh*QL + q0)*KL;
    const int r0 = (w - 8)*2;
    #pragma unroll
    for (int rr=0; rr<2; ++rr){
      const int row = r0 + rr;
      const _Float16* sr = sb + (size_t)row*KL;
      float* orow = ob + (size_t)row*KL;
      #pragma unroll
      for (int ch=0; ch<8; ++ch){
        f16x4 hv = *(const f16x4*)&sr[ch*256 + lane*4];
        f32x4 v;
        v[0]=(float)hv[0]; v[1]=(float)hv[1]; v[2]=(float)hv[2]; v[3]=(float)hv[3];
        *(f32x4*)&orow[ch*256 + lane*4] = v;
      }
    }
  }
  __syncthreads();

  // epilogue: combine K-halves, write ao (bf16, 128B/row contiguous); S16 already normalized
  {
    const int row = tid >> 6, d = tid & 63;
    float o = osum[d >> 4][row][d & 15] + osum[4 + (d >> 4)][row][d & 15];
    ao[((size_t)b*QL + q0 + row)*CH + h*HD + d] = f2bf(o);
  }
}

// ---------------- round-9 fused fallback (used when ws_size < split requirement) ----------------
template<int BITS>
__global__ __launch_bounds__(1024, 1) void k_attn(const u16* __restrict__ qh, const u16* __restrict__ kh,
                                              const _Float16* __restrict__ vt, const float* __restrict__ bias,
                                              const void* __restrict__ maskp, const int* __restrict__ flag,
                                              const unsigned* __restrict__ mbits,
                                              float* __restrict__ attn, u16* __restrict__ ao){
  __shared__ _Float16 Sh[16][SH_STRIDE];
  __shared__ float osum[8][16][17];
  __shared__ float wsum[16][16];
  __shared__ float inv_l[16];
  const int qt = BITS ? blockIdx.x : blockIdx.y;
  const int h  = BITS ? blockIdx.y : blockIdx.x;
  const int b  = blockIdx.z;
  const int q0 = qt*16, bh = b*NH + h;
  const int tid = threadIdx.x, lane = tid & 63, w = tid >> 6;
  const int lr = lane & 15, lg = lane >> 4;
  const u16* qb = qh + ((size_t)bh*QL + q0)*HD;
  const bf16x8 qf0 = *(const bf16x8*)&qb[lr*HD +      lg*8];
  const bf16x8 qf1 = *(const bf16x8*)&qb[lr*HD + 32 + lg*8];
  const float* bb = bias + ((size_t)bh*QL + q0)*KL;
  const u16* khb = kh + (size_t)bh*KL*HD;
  const _Float16* vtb = vt + (size_t)bh*HD*KL;
  const int c0 = w*128;

  f32x4 bi[8];
  unsigned mwd[8];
  #pragma unroll
  for (int ct=0; ct<8; ++ct){
    const int cb = c0 + ct*16 + lg*4;
    bi[ct] = *(const f32x4*)&bb[(size_t)lr*KL + cb];
    if (BITS) mwd[ct] = mbits[((size_t)b*QL + q0 + lr)*(KL/32) + (cb>>5)];
  }
  const int isbool = BITS ? 0 : *flag;
  const unsigned char* mb8 = (const unsigned char*)maskp + ((size_t)b*QL + q0)*KL;
  const int* mb32 = (const int*)maskp + ((size_t)b*QL + q0)*KL;

  float ps = 0.f;
  #pragma unroll
  for (int ct=0; ct<8; ++ct){
    const int cb = c0 + ct*16 + lg*4;
    f32x4 acc = bi[ct];
    const int kcol = c0 + ct*16 + lr;
    bf16x8 kf0 = *(const bf16x8*)&khb[(size_t)kcol*HD +      lg*8];
    bf16x8 kf1 = *(const bf16x8*)&khb[(size_t)kcol*HD + 32 + lg*8];
    acc = __builtin_amdgcn_mfma_f32_16x16x32_bf16(kf0, qf0, acc, 0,0,0);
    acc = __builtin_amdgcn_mfma_f32_16x16x32_bf16(kf1, qf1, acc, 0,0,0);
    unsigned msel;
    i32x4 mv;
    if (BITS){
      msel = (mwd[ct] >> (cb & 31)) & 0xFu;
    } else if (isbool){
      unsigned mw = *(const unsigned*)&mb8[(size_t)lr*KL + cb];
      msel = (mw&1u) | ((mw>>7)&2u) | ((mw>>14)&4u) | ((mw>>21)&8u);
    } else {
      mv = *(const i32x4*)&mb32[(size_t)lr*KL + cb];
      msel = (unsigned)((mv[0]&1) | ((mv[1]&1)<<1) | ((mv[2]&1)<<2) | ((mv[3]&1)<<3));
    }
    f16x4 sv;
    #pragma unroll
    for (int r=0;r<4;++r){
      float e = ((msel >> r) & 1u) ? 0.f : __expf(acc[r]);
      sv[r] = (_Float16)e;
      ps += e;
    }
    *(f16x4*)&Sh[lr][cb] = sv;
  }
  ps += __shfl_xor(ps, 16);
  ps += __shfl_xor(ps, 32);
  if (lane < 16) wsum[w][lr] = ps;
  __syncthreads();
  if (tid < 16){
    float s = 0.f;
    #pragma unroll
    for (int ww=0; ww<16; ++ww) s += wsum[ww][tid];
    inv_l[tid] = 1.f / s;
  }
  __syncthreads();

  if (w < 8){
    const int d0 = (w & 3)*16, kb0 = (w >> 2)*1024;
    f32x4 oacc = {};
    #pragma unroll
    for (int kb=0; kb<4; ++kb){
      f16x8 vf[8];
      #pragma unroll
      for (int i=0;i<8;++i)
        vf[i] = *(const f16x8*)&vtb[(size_t)(d0+lr)*KL + kb0 + kb*256 + i*32 + lg*8];
      #pragma unroll
      for (int i=0;i<8;++i){
        f16x8 a = *(const f16x8*)&Sh[lr][kb0 + kb*256 + i*32 + lg*8];
        oacc = __builtin_amdgcn_mfma_f32_16x16x32_f16(a, vf[i], oacc, 0,0,0);
      }
    }
    #pragma unroll
    for (int r=0;r<4;++r) osum[w][lg*4+r][lr] = oacc[r];
  } else {
    float* ob = attn + ((size_t)bh*QL + q0)*KL;
    const int r0 = (w - 8)*2;
    #pragma unroll
    for (int rr=0; rr<2; ++rr){
      const int row = r0 + rr;
      const float ivr = inv_l[row];
      #pragma unroll
      for (int ch=0; ch<8; ++ch){
        f16x4 hv = *(const f16x4*)&Sh[row][ch*256 + lane*4];
        f32x4 v;
        v[0]=(float)hv[0]*ivr; v[1]=(float)hv[1]*ivr; v[2]=(float)hv[2]*ivr; v[3]=(float)hv[3]*ivr;
        *(f32x4*)&ob[(size_t)row*KL + ch*256 + lane*4] = v;
      }
    }
  }
  __syncthreads();
  {
    const int row = tid >> 6, d = tid & 63;
    float o = (osum[d >> 4][row][d & 15] + osum[4 + (d >> 4)][row][d & 15]) * inv_l[row];
    ao[((size_t)b*QL + q0 + row)*CH + h*HD + d] = f2bf(o);
  }
}

extern "C" void kernel_launch(void* const* d_in, const int* in_sizes, int n_in,
                              void* d_out, int out_size, void* d_ws, size_t ws_size,
                              hipStream_t stream){
  const float* q    = (const float*)d_in[0];
  const float* k    = (const float*)d_in[1];
  const float* v    = (const float*)d_in[2];
  const void*  mask = d_in[3];
  const float* bias = (const float*)d_in[4];
  const float* Wq   = (const float*)d_in[5];
  const float* bq   = (const float*)d_in[6];
  const float* Wk   = (const float*)d_in[7];
  const float* bk   = (const float*)d_in[8];
  const float* Wv   = (const float*)d_in[9];
  const float* bv   = (const float*)d_in[10];
  const float* Wo   = (const float*)d_in[11];
  const float* bo   = (const float*)d_in[12];

  char* wsb = (char*)d_ws;
  int* flag = (int*)wsb;
  u16* qh = (u16*)(wsb + 256);
  u16* kh = (u16*)(wsb + 256 + 1*8388608);
  u16* vt = (u16*)(wsb + 256 + 2*8388608);
  u16* ao = (u16*)(wsb + 256 + 3*8388608);
  u16* wt = (u16*)(wsb + 256 + 4*8388608);
  unsigned* mbits = (unsigned*)(wsb + 256 + 5*8388608);
  _Float16* S16 = (_Float16*)(wsb + 256 + 5*8388608 + 1048576);
  const size_t need_bits  = 256 + 5ull*8388608 + 1048576;
  const size_t need_split = need_bits + (size_t)NB*NH*QL*KL*2;   // +268MB
  const bool usebits  = (ws_size >= need_bits);
  const bool usesplit = (ws_size >= need_split);

  float* out  = (float*)d_out;
  float* attn = out + (size_t)NB*QL*CH;

  k_detect<<<1, 256, 0, stream>>>((const unsigned int*)mask, flag);
  if (usebits)
    k_maskpack<<<dim3(1024), 256, 0, stream>>>(mask, flag, mbits);
  k_transpose<<<dim3(32,32,4), 256, 0, stream>>>(Wq, Wk, Wv, Wo, wt);
  k_gemm_qkv<<<dim3(16,64,3), 256, 0, stream>>>(q, k, v, wt, bq, bk, bv, qh, kh, vt);
  if (usesplit){
    k_qk<<<dim3(128,16,2), 1024, 0, stream>>>(qh, kh, bias, mbits, S16);
    k_pv<<<dim3(128,16,2), 1024, 0, stream>>>(S16, (const _Float16*)vt, attn, ao);
  } else if (usebits){
    k_attn<1><<<dim3(128,16,2), 1024, 0, stream>>>(qh, kh, (const _Float16*)vt, bias, mask, flag, mbits, attn, ao);
  } else {
    k_attn<0><<<dim3(16,128,2), 1024, 0, stream>>>(qh, kh, (const _Float16*)vt, bias, mask, flag, mbits, attn, ao);
  }
  k_gemm_out<<<dim3(16,64), 256, 0, stream>>>(ao, wt + 3145728, bo, out);
}

// Round 13
// 673.487 us; speedup vs baseline: 1.1373x; 1.1373x over previous
//
#include <hip/hip_runtime.h>
#include <hip/hip_bf16.h>

// MultiHeadAttention fused pipeline for MI355X (gfx950).
// Outputs: [0] out (2*2048*1024 f32), [1] attn (2*16*2048*2048 f32), concatenated in d_out.
// ws layout: [flag:256B][qh 8MB][kh 8MB][vt 8MB][ao 8MB][wt 4x2MB][mbits 1MB] = ~41MB.

typedef __attribute__((ext_vector_type(8))) short bf16x8;
typedef __attribute__((ext_vector_type(8))) _Float16 f16x8;
typedef __attribute__((ext_vector_type(4))) float f32x4;
typedef __attribute__((ext_vector_type(4))) int i32x4;
typedef __attribute__((ext_vector_type(4))) _Float16 f16x4;
typedef unsigned short u16;

#define NB 2
#define QL 2048
#define KL 2048
#define CH 1024
#define NH 16
#define HD 64
#define SH_STRIDE 2600   // fused-fallback stride
#define PS_STRIDE 2088   // pipe Sh stride: row 4176B, 16B-aligned, dw-stride%32=20 (spread banks)

__device__ __forceinline__ u16 f2bf(float f){
  unsigned u = __float_as_uint(f);
  u += 0x7fffu + ((u >> 16) & 1u);   // RNE
  return (u16)(u >> 16);
}
__device__ __forceinline__ u16 f2h(float f){
  _Float16 h = (_Float16)f;
  return *(u16*)&h;
}

// ---------------- mask dtype detector: int32 0/1 vs packed bool bytes ----------------
__global__ void k_detect(const unsigned int* __restrict__ m, int* __restrict__ flag){
  unsigned v = m[threadIdx.x];
  unsigned long long b = __ballot(v > 1u);
  __shared__ int r[4];
  if ((threadIdx.x & 63) == 0) r[threadIdx.x >> 6] = (b != 0ULL);
  __syncthreads();
  if (threadIdx.x == 0) *flag = (r[0] | r[1] | r[2] | r[3]);
}

// ---------------- mask -> 1 bit/elem (1MB total; stays L2/L3-resident) ----------------
__global__ __launch_bounds__(256) void k_maskpack(const void* __restrict__ maskp, const int* __restrict__ flag,
                                                  unsigned* __restrict__ mbits){
  const int idx = blockIdx.x*256 + threadIdx.x;   // 262144 words, 32 mask elems each
  unsigned out = 0;
  if (*flag){
    const unsigned* m8 = (const unsigned*)maskp + (size_t)idx*8;
    #pragma unroll
    for (int j=0;j<8;++j){
      unsigned wv = m8[j];
      out |= ((wv & 1u) | ((wv>>7)&2u) | ((wv>>14)&4u) | ((wv>>21)&8u)) << (4*j);
    }
  } else {
    const i32x4* m32 = (const i32x4*)maskp + (size_t)idx*8;
    #pragma unroll
    for (int j=0;j<8;++j){
      i32x4 v = m32[j];
      out |= (unsigned)((v[0]&1) | ((v[1]&1)<<1) | ((v[2]&1)<<2) | ((v[3]&1)<<3)) << (4*j);
    }
  }
  mbits[idx] = out;
}

// ---------------- weight transpose + bf16 convert: W[in][out] -> Wt[out][in] ----------------
__global__ __launch_bounds__(256) void k_transpose(const float* __restrict__ Wq, const float* __restrict__ Wk,
                                                   const float* __restrict__ Wv, const float* __restrict__ Wo,
                                                   u16* __restrict__ wt){
  const float* src = blockIdx.z==0 ? Wq : blockIdx.z==1 ? Wk : blockIdx.z==2 ? Wv : Wo;
  u16* dst = wt + (size_t)blockIdx.z * CH * CH;
  __shared__ float t[32][33];
  const int x = blockIdx.x*32, y = blockIdx.y*32;
  const int tx = threadIdx.x & 31, ty = threadIdx.x >> 5;
  #pragma unroll
  for (int j=0;j<32;j+=8) t[ty+j][tx] = src[(size_t)(y+ty+j)*CH + x + tx];
  __syncthreads();
  #pragma unroll
  for (int j=0;j<32;j+=8) dst[(size_t)(x+ty+j)*CH + y + tx] = f2bf(t[tx][ty+j]);
}

// ---------------- merged QKV projection GEMM ----------------
__global__ __launch_bounds__(256) void k_gemm_qkv(const float* __restrict__ q, const float* __restrict__ k,
                                                  const float* __restrict__ v, const u16* __restrict__ wt,
                                                  const float* __restrict__ bq, const float* __restrict__ bk,
                                                  const float* __restrict__ bv,
                                                  u16* __restrict__ qh, u16* __restrict__ kh, u16* __restrict__ vt){
  const int z = blockIdx.z;
  const float* A = z==0 ? q : z==1 ? k : v;
  const u16* Bt = wt + (size_t)z*CH*CH;
  const float* bias = z==0 ? bq : z==1 ? bk : bv;
  u16* Cp = z==0 ? qh : z==1 ? kh : vt;
  const float scale = (z==0) ? 0.03125f : 1.0f;

  __shared__ u16 As[64][72];
  __shared__ u16 Bs[64][72];
  const int m0 = blockIdx.y*64, n0 = blockIdx.x*64;
  const int tid = threadIdx.x, lane = tid & 63, w = tid >> 6;
  const int wm = w >> 1, wn = w & 1;
  const int lr = lane & 15, lg = lane >> 4;
  f32x4 acc[2][2] = {};
  for (int k0 = 0; k0 < CH; k0 += 64){
    #pragma unroll
    for (int j=0;j<4;++j){
      int idx = tid + 256*j, r = idx >> 4, c = (idx & 15)*4;
      float4 vv = *(const float4*)&A[(size_t)(m0+r)*CH + k0 + c];
      ushort4 s; s.x=f2bf(vv.x); s.y=f2bf(vv.y); s.z=f2bf(vv.z); s.w=f2bf(vv.w);
      *(ushort4*)&As[r][c] = s;
    }
    #pragma unroll
    for (int j=0;j<2;++j){
      int idx = tid + 256*j, r = idx >> 3, c = (idx & 7)*8;
      *(uint4*)&Bs[r][c] = *(const uint4*)&Bt[(size_t)(n0+r)*CH + k0 + c];
    }
    __syncthreads();
    #pragma unroll
    for (int kk=0; kk<2; ++kk){
      bf16x8 a0 = *(const bf16x8*)&As[wm*32      + lr][kk*32 + lg*8];
      bf16x8 a1 = *(const bf16x8*)&As[wm*32 + 16 + lr][kk*32 + lg*8];
      bf16x8 b0 = *(const bf16x8*)&Bs[wn*32      + lr][kk*32 + lg*8];
      bf16x8 b1 = *(const bf16x8*)&Bs[wn*32 + 16 + lr][kk*32 + lg*8];
      acc[0][0] = __builtin_amdgcn_mfma_f32_16x16x32_bf16(a0,b0,acc[0][0],0,0,0);
      acc[0][1] = __builtin_amdgcn_mfma_f32_16x16x32_bf16(a0,b1,acc[0][1],0,0,0);
      acc[1][0] = __builtin_amdgcn_mfma_f32_16x16x32_bf16(a1,b0,acc[1][0],0,0,0);
      acc[1][1] = __builtin_amdgcn_mfma_f32_16x16x32_bf16(a1,b1,acc[1][1],0,0,0);
    }
    __syncthreads();
  }
  #pragma unroll
  for (int fi=0;fi<2;++fi)
  #pragma unroll
  for (int fj=0;fj<2;++fj)
  #pragma unroll
  for (int r=0;r<4;++r){
    int row = m0 + wm*32 + fi*16 + lg*4 + r;
    int col = n0 + wn*32 + fj*16 + lr;
    float val = (acc[fi][fj][r] + bias[col]) * scale;
    int bb = row >> 11, ll = row & 2047, hh = col >> 6, dd = col & 63;
    if (z < 2){
      Cp[(((size_t)(bb*NH+hh)*QL + ll) << 6) + dd] = f2bf(val);
    } else {
      Cp[(((size_t)(bb*NH+hh) << 6) + dd)*KL + ll] = f2h(val);   // vt in f16 for f16-MFMA PV
    }
  }
}

// ---------------- final projection GEMM: out = ao @ Wo^T + bo (f32 out) ----------------
__global__ __launch_bounds__(256) void k_gemm_out(const u16* __restrict__ Ap, const u16* __restrict__ Bt,
                                                  const float* __restrict__ bias, float* __restrict__ Cp){
  __shared__ u16 As[64][72];
  __shared__ u16 Bs[64][72];
  const int m0 = blockIdx.y*64, n0 = blockIdx.x*64;
  const int tid = threadIdx.x, lane = tid & 63, w = tid >> 6;
  const int wm = w >> 1, wn = w & 1;
  const int lr = lane & 15, lg = lane >> 4;
  f32x4 acc[2][2] = {};
  for (int k0 = 0; k0 < CH; k0 += 64){
    #pragma unroll
    for (int j=0;j<2;++j){
      int idx = tid + 256*j, r = idx >> 3, c = (idx & 7)*8;
      *(uint4*)&As[r][c] = *(const uint4*)&Ap[(size_t)(m0+r)*CH + k0 + c];
      *(uint4*)&Bs[r][c] = *(const uint4*)&Bt[(size_t)(n0+r)*CH + k0 + c];
    }
    __syncthreads();
    #pragma unroll
    for (int kk=0; kk<2; ++kk){
      bf16x8 a0 = *(const bf16x8*)&As[wm*32      + lr][kk*32 + lg*8];
      bf16x8 a1 = *(const bf16x8*)&As[wm*32 + 16 + lr][kk*32 + lg*8];
      bf16x8 b0 = *(const bf16x8*)&Bs[wn*32      + lr][kk*32 + lg*8];
      bf16x8 b1 = *(const bf16x8*)&Bs[wn*32 + 16 + lr][kk*32 + lg*8];
      acc[0][0] = __builtin_amdgcn_mfma_f32_16x16x32_bf16(a0,b0,acc[0][0],0,0,0);
      acc[0][1] = __builtin_amdgcn_mfma_f32_16x16x32_bf16(a0,b1,acc[0][1],0,0,0);
      acc[1][0] = __builtin_amdgcn_mfma_f32_16x16x32_bf16(a1,b0,acc[1][0],0,0,0);
      acc[1][1] = __builtin_amdgcn_mfma_f32_16x16x32_bf16(a1,b1,acc[1][1],0,0,0);
    }
    __syncthreads();
  }
  #pragma unroll
  for (int fi=0;fi<2;++fi)
  #pragma unroll
  for (int fj=0;fj<2;++fj)
  #pragma unroll
  for (int r=0;r<4;++r){
    int row = m0 + wm*32 + fi*16 + lg*4 + r;
    int col = n0 + wn*32 + fj*16 + lr;
    Cp[(size_t)row*CH + col] = acc[fi][fj][r] + bias[col];
  }
}

// ---------------- persistent producer-consumer attention (1 block/CU, software pipeline) ----------------
// Grid 256 blocks (8 qt-groups x 16 h x 2 b); each block runs 16 tiles of 16 q-rows.
// Waves 0-7: producers — QK^T(swapped)+bias+mask+exp for tile t into Sh[t&1] (each wave 256 cols).
// Waves 8-11: writers — burst-write normalized attn of tile t-1 (4 rows each, 1KB/instr).
// Waves 12-15: PV — d-strip (w-12)*16, full K, f16 MFMA; per-tile ao write (no cross-wave reduce).
// One __syncthreads per tile; read-stream (producers) and write-stream (writers) overlap fully,
// while writer concurrency stays at R9's clean level (tight per-row bursts, full 256B lines).
__global__ __launch_bounds__(1024, 1) void k_attn_pipe(const u16* __restrict__ qh, const u16* __restrict__ kh,
                                              const _Float16* __restrict__ vt, const float* __restrict__ bias,
                                              const unsigned* __restrict__ mbits,
                                              float* __restrict__ attn, u16* __restrict__ ao){
  __shared__ _Float16 Sh[2][16][PS_STRIDE];   // 133.6 KB
  __shared__ float wsum[2][8][16];            // 1 KB
  const int h = blockIdx.y, b = blockIdx.z;
  const int bh = b*NH + h;
  const int tid = threadIdx.x, lane = tid & 63, w = tid >> 6;  // w 0..15
  const int lr = lane & 15, lg = lane >> 4;
  const u16* khb = kh + (size_t)bh*KL*HD;
  const _Float16* vtb = vt + (size_t)bh*HD*KL;

  for (int it = 0; it <= 16; ++it){
    __syncthreads();
    if (w < 8){
      if (it < 16){
        // ---- producer: tile it -> Sh[it&1] ----
        const int qt = blockIdx.x*16 + it, q0 = qt*16;
        const int buf = it & 1, c0 = w*256;
        const u16* qb = qh + ((size_t)bh*QL + q0)*HD;
        const bf16x8 qf0 = *(const bf16x8*)&qb[lr*HD +      lg*8];
        const bf16x8 qf1 = *(const bf16x8*)&qb[lr*HD + 32 + lg*8];
        const float* bb = bias + ((size_t)bh*QL + q0)*KL;
        float ps = 0.f;
        #pragma unroll
        for (int half=0; half<2; ++half){
          f32x4 bi[8];
          unsigned mwd[8];
          #pragma unroll
          for (int ct=0; ct<8; ++ct){
            const int cb = c0 + half*128 + ct*16 + lg*4;
            bi[ct] = *(const f32x4*)&bb[(size_t)lr*KL + cb];
            mwd[ct] = mbits[((size_t)b*QL + q0 + lr)*(KL/32) + (cb>>5)];
          }
          #pragma unroll
          for (int ct=0; ct<8; ++ct){
            const int cb = c0 + half*128 + ct*16 + lg*4;
            f32x4 acc = bi[ct];
            const int kcol = c0 + half*128 + ct*16 + lr;
            bf16x8 kf0 = *(const bf16x8*)&khb[(size_t)kcol*HD +      lg*8];
            bf16x8 kf1 = *(const bf16x8*)&khb[(size_t)kcol*HD + 32 + lg*8];
            acc = __builtin_amdgcn_mfma_f32_16x16x32_bf16(kf0, qf0, acc, 0,0,0);   // D = S^T frag
            acc = __builtin_amdgcn_mfma_f32_16x16x32_bf16(kf1, qf1, acc, 0,0,0);
            const unsigned msel = (mwd[ct] >> (cb & 31)) & 0xFu;
            f16x4 sv;
            #pragma unroll
            for (int r=0;r<4;++r){
              float e = ((msel >> r) & 1u) ? 0.f : __expf(acc[r]);   // bounded logits
              sv[r] = (_Float16)e;
              ps += e;
            }
            *(f16x4*)&Sh[buf][lr][cb] = sv;
          }
        }
        ps += __shfl_xor(ps, 16);
        ps += __shfl_xor(ps, 32);
        if (lane < 16) wsum[buf][w][lr] = ps;
      }
    } else if (it >= 1){
      // ---- consumer: tile it-1 from Sh[(it-1)&1] ----
      const int t = it - 1;
      const int qt = blockIdx.x*16 + t, q0 = qt*16;
      const int buf = t & 1;
      if (w < 12){
        // writer wave: 4 rows, normalized f32 attn, 1KB contiguous per instruction
        float* ob = attn + ((size_t)bh*QL + q0)*KL;
        const int r0 = (w - 8)*4;
        #pragma unroll
        for (int rr=0; rr<4; ++rr){
          const int row = r0 + rr;
          float s = 0.f;
          #pragma unroll
          for (int p=0;p<8;++p) s += wsum[buf][p][row];
          const float ivr = 1.f / s;
          float* orow = ob + (size_t)row*KL;
          #pragma unroll
          for (int ch=0; ch<8; ++ch){
            f16x4 hv = *(const f16x4*)&Sh[buf][row][ch*256 + lane*4];
            f32x4 v;
            v[0]=(float)hv[0]*ivr; v[1]=(float)hv[1]*ivr; v[2]=(float)hv[2]*ivr; v[3]=(float)hv[3]*ivr;
            *(f32x4*)&orow[ch*256 + lane*4] = v;
          }
        }
      } else {
        // PV wave: d-strip (w-12)*16, full K; 8-deep batched loads; direct ao write
        const int d0 = (w - 12)*16;
        f32x4 oacc = {};
        #pragma unroll
        for (int kb=0; kb<8; ++kb){
          f16x8 vf[8], af[8];
          #pragma unroll
          for (int i=0;i<8;++i){
            vf[i] = *(const f16x8*)&vtb[(size_t)(d0+lr)*KL + kb*256 + i*32 + lg*8];
            af[i] = *(const f16x8*)&Sh[buf][lr][kb*256 + i*32 + lg*8];
          }
          #pragma unroll
          for (int i=0;i<8;++i)
            oacc = __builtin_amdgcn_mfma_f32_16x16x32_f16(af[i], vf[i], oacc, 0,0,0);
        }
        #pragma unroll
        for (int r=0;r<4;++r){
          const int row = lg*4 + r;        // D: row=(lane>>4)*4+reg (q-row), col=lane&15 (d)
          float s = 0.f;
          #pragma unroll
          for (int p=0;p<8;++p) s += wsum[buf][p][row];
          ao[((size_t)b*QL + q0 + row)*CH + h*HD + d0 + lr] = f2bf(oacc[r] / s);
        }
      }
    }
  }
}

// ---------------- round-9 fused fallback (used when mbits workspace unavailable) ----------------
template<int BITS>
__global__ __launch_bounds__(1024, 1) void k_attn(const u16* __restrict__ qh, const u16* __restrict__ kh,
                                              const _Float16* __restrict__ vt, const float* __restrict__ bias,
                                              const void* __restrict__ maskp, const int* __restrict__ flag,
                                              const unsigned* __restrict__ mbits,
                                              float* __restrict__ attn, u16* __restrict__ ao){
  __shared__ _Float16 Sh[16][SH_STRIDE];
  __shared__ float osum[8][16][17];
  __shared__ float wsum[16][16];
  __shared__ float inv_l[16];
  const int qt = BITS ? blockIdx.x : blockIdx.y;
  const int h  = BITS ? blockIdx.y : blockIdx.x;
  const int b  = blockIdx.z;
  const int q0 = qt*16, bh = b*NH + h;
  const int tid = threadIdx.x, lane = tid & 63, w = tid >> 6;
  const int lr = lane & 15, lg = lane >> 4;
  const u16* qb = qh + ((size_t)bh*QL + q0)*HD;
  const bf16x8 qf0 = *(const bf16x8*)&qb[lr*HD +      lg*8];
  const bf16x8 qf1 = *(const bf16x8*)&qb[lr*HD + 32 + lg*8];
  const float* bb = bias + ((size_t)bh*QL + q0)*KL;
  const u16* khb = kh + (size_t)bh*KL*HD;
  const _Float16* vtb = vt + (size_t)bh*HD*KL;
  const int c0 = w*128;

  f32x4 bi[8];
  unsigned mwd[8];
  #pragma unroll
  for (int ct=0; ct<8; ++ct){
    const int cb = c0 + ct*16 + lg*4;
    bi[ct] = *(const f32x4*)&bb[(size_t)lr*KL + cb];
    if (BITS) mwd[ct] = mbits[((size_t)b*QL + q0 + lr)*(KL/32) + (cb>>5)];
  }
  const int isbool = BITS ? 0 : *flag;
  const unsigned char* mb8 = (const unsigned char*)maskp + ((size_t)b*QL + q0)*KL;
  const int* mb32 = (const int*)maskp + ((size_t)b*QL + q0)*KL;

  float ps = 0.f;
  #pragma unroll
  for (int ct=0; ct<8; ++ct){
    const int cb = c0 + ct*16 + lg*4;
    f32x4 acc = bi[ct];
    const int kcol = c0 + ct*16 + lr;
    bf16x8 kf0 = *(const bf16x8*)&khb[(size_t)kcol*HD +      lg*8];
    bf16x8 kf1 = *(const bf16x8*)&khb[(size_t)kcol*HD + 32 + lg*8];
    acc = __builtin_amdgcn_mfma_f32_16x16x32_bf16(kf0, qf0, acc, 0,0,0);
    acc = __builtin_amdgcn_mfma_f32_16x16x32_bf16(kf1, qf1, acc, 0,0,0);
    unsigned msel;
    i32x4 mv;
    if (BITS){
      msel = (mwd[ct] >> (cb & 31)) & 0xFu;
    } else if (isbool){
      unsigned mw = *(const unsigned*)&mb8[(size_t)lr*KL + cb];
      msel = (mw&1u) | ((mw>>7)&2u) | ((mw>>14)&4u) | ((mw>>21)&8u);
    } else {
      mv = *(const i32x4*)&mb32[(size_t)lr*KL + cb];
      msel = (unsigned)((mv[0]&1) | ((mv[1]&1)<<1) | ((mv[2]&1)<<2) | ((mv[3]&1)<<3));
    }
    f16x4 sv;
    #pragma unroll
    for (int r=0;r<4;++r){
      float e = ((msel >> r) & 1u) ? 0.f : __expf(acc[r]);
      sv[r] = (_Float16)e;
      ps += e;
    }
    *(f16x4*)&Sh[lr][cb] = sv;
  }
  ps += __shfl_xor(ps, 16);
  ps += __shfl_xor(ps, 32);
  if (lane < 16) wsum[w][lr] = ps;
  __syncthreads();
  if (tid < 16){
    float s = 0.f;
    #pragma unroll
    for (int ww=0; ww<16; ++ww) s += wsum[ww][tid];
    inv_l[tid] = 1.f / s;
  }
  __syncthreads();

  if (w < 8){
    const int d0 = (w & 3)*16, kb0 = (w >> 2)*1024;
    f32x4 oacc = {};
    #pragma unroll
    for (int kb=0; kb<4; ++kb){
      f16x8 vf[8];
      #pragma unroll
      for (int i=0;i<8;++i)
        vf[i] = *(const f16x8*)&vtb[(size_t)(d0+lr)*KL + kb0 + kb*256 + i*32 + lg*8];
      #pragma unroll
      for (int i=0;i<8;++i){
        f16x8 a = *(const f16x8*)&Sh[lr][kb0 + kb*256 + i*32 + lg*8];
        oacc = __builtin_amdgcn_mfma_f32_16x16x32_f16(a, vf[i], oacc, 0,0,0);
      }
    }
    #pragma unroll
    for (int r=0;r<4;++r) osum[w][lg*4+r][lr] = oacc[r];
  } else {
    float* ob = attn + ((size_t)bh*QL + q0)*KL;
    const int r0 = (w - 8)*2;
    #pragma unroll
    for (int rr=0; rr<2; ++rr){
      const int row = r0 + rr;
      const float ivr = inv_l[row];
      #pragma unroll
      for (int ch=0; ch<8; ++ch){
        f16x4 hv = *(const f16x4*)&Sh[row][ch*256 + lane*4];
        f32x4 v;
        v[0]=(float)hv[0]*ivr; v[1]=(float)hv[1]*ivr; v[2]=(float)hv[2]*ivr; v[3]=(float)hv[3]*ivr;
        *(f32x4*)&ob[(size_t)row*KL + ch*256 + lane*4] = v;
      }
    }
  }
  __syncthreads();
  {
    const int row = tid >> 6, d = tid & 63;
    float o = (osum[d >> 4][row][d & 15] + osum[4 + (d >> 4)][row][d & 15]) * inv_l[row];
    ao[((size_t)b*QL + q0 + row)*CH + h*HD + d] = f2bf(o);
  }
}

extern "C" void kernel_launch(void* const* d_in, const int* in_sizes, int n_in,
                              void* d_out, int out_size, void* d_ws, size_t ws_size,
                              hipStream_t stream){
  const float* q    = (const float*)d_in[0];
  const float* k    = (const float*)d_in[1];
  const float* v    = (const float*)d_in[2];
  const void*  mask = d_in[3];
  const float* bias = (const float*)d_in[4];
  const float* Wq   = (const float*)d_in[5];
  const float* bq   = (const float*)d_in[6];
  const float* Wk   = (const float*)d_in[7];
  const float* bk   = (const float*)d_in[8];
  const float* Wv   = (const float*)d_in[9];
  const float* bv   = (const float*)d_in[10];
  const float* Wo   = (const float*)d_in[11];
  const float* bo   = (const float*)d_in[12];

  char* wsb = (char*)d_ws;
  int* flag = (int*)wsb;
  u16* qh = (u16*)(wsb + 256);
  u16* kh = (u16*)(wsb + 256 + 1*8388608);
  u16* vt = (u16*)(wsb + 256 + 2*8388608);
  u16* ao = (u16*)(wsb + 256 + 3*8388608);
  u16* wt = (u16*)(wsb + 256 + 4*8388608);
  unsigned* mbits = (unsigned*)(wsb + 256 + 5*8388608);
  const size_t need_bits = 256 + 5ull*8388608 + 1048576;
  const bool usebits = (ws_size >= need_bits);

  float* out  = (float*)d_out;
  float* attn = out + (size_t)NB*QL*CH;

  k_detect<<<1, 256, 0, stream>>>((const unsigned int*)mask, flag);
  if (usebits)
    k_maskpack<<<dim3(1024), 256, 0, stream>>>(mask, flag, mbits);
  k_transpose<<<dim3(32,32,4), 256, 0, stream>>>(Wq, Wk, Wv, Wo, wt);
  k_gemm_qkv<<<dim3(16,64,3), 256, 0, stream>>>(q, k, v, wt, bq, bk, bv, qh, kh, vt);
  if (usebits)
    k_attn_pipe<<<dim3(8,16,2), 1024, 0, stream>>>(qh, kh, (const _Float16*)vt, bias, mbits, attn, ao);
  else
    k_attn<0><<<dim3(16,128,2), 1024, 0, stream>>>(qh, kh, (const _Float16*)vt, bias, mask, flag, mbits, attn, ao);
  k_gemm_out<<<dim3(16,64), 256, 0, stream>>>(ao, wt + 3145728, bo, out);
}

// Round 14
// 657.546 us; speedup vs baseline: 1.1649x; 1.0242x over previous
//
#include <hip/hip_runtime.h>
#include <hip/hip_bf16.h>

// MultiHeadAttention fused pipeline for MI355X (gfx950).
// Outputs: [0] out (2*2048*1024 f32), [1] attn (2*16*2048*2048 f32), concatenated in d_out.
// ws layout: [flag:256B][qh 8MB][kh 8MB][vt 8MB][ao 8MB][wt 4x2MB][mbits 1MB] = ~41MB.

typedef __attribute__((ext_vector_type(8))) short bf16x8;
typedef __attribute__((ext_vector_type(8))) _Float16 f16x8;
typedef __attribute__((ext_vector_type(4))) float f32x4;
typedef __attribute__((ext_vector_type(4))) int i32x4;
typedef __attribute__((ext_vector_type(4))) _Float16 f16x4;
typedef unsigned short u16;

#define NB 2
#define QL 2048
#define KL 2048
#define CH 1024
#define NH 16
#define HD 64
#define SH_STRIDE 2600   // fused-fallback stride
#define PS_STRIDE 2088   // pipe Sh stride: row 4176B, 16B-aligned, dw-stride%32=20 (spread banks)
#define TPB 2            // tiles per pipe block: keeps concurrent (h,b) span = 4 pairs -> K/V L2-resident

__device__ __forceinline__ u16 f2bf(float f){
  unsigned u = __float_as_uint(f);
  u += 0x7fffu + ((u >> 16) & 1u);   // RNE
  return (u16)(u >> 16);
}
__device__ __forceinline__ u16 f2h(float f){
  _Float16 h = (_Float16)f;
  return *(u16*)&h;
}

// ---------------- mask dtype detector: int32 0/1 vs packed bool bytes ----------------
__global__ void k_detect(const unsigned int* __restrict__ m, int* __restrict__ flag){
  unsigned v = m[threadIdx.x];
  unsigned long long b = __ballot(v > 1u);
  __shared__ int r[4];
  if ((threadIdx.x & 63) == 0) r[threadIdx.x >> 6] = (b != 0ULL);
  __syncthreads();
  if (threadIdx.x == 0) *flag = (r[0] | r[1] | r[2] | r[3]);
}

// ---------------- mask -> 1 bit/elem (1MB total; stays L2/L3-resident) ----------------
__global__ __launch_bounds__(256) void k_maskpack(const void* __restrict__ maskp, const int* __restrict__ flag,
                                                  unsigned* __restrict__ mbits){
  const int idx = blockIdx.x*256 + threadIdx.x;   // 262144 words, 32 mask elems each
  unsigned out = 0;
  if (*flag){
    const unsigned* m8 = (const unsigned*)maskp + (size_t)idx*8;
    #pragma unroll
    for (int j=0;j<8;++j){
      unsigned wv = m8[j];
      out |= ((wv & 1u) | ((wv>>7)&2u) | ((wv>>14)&4u) | ((wv>>21)&8u)) << (4*j);
    }
  } else {
    const i32x4* m32 = (const i32x4*)maskp + (size_t)idx*8;
    #pragma unroll
    for (int j=0;j<8;++j){
      i32x4 v = m32[j];
      out |= (unsigned)((v[0]&1) | ((v[1]&1)<<1) | ((v[2]&1)<<2) | ((v[3]&1)<<3)) << (4*j);
    }
  }
  mbits[idx] = out;
}

// ---------------- weight transpose + bf16 convert: W[in][out] -> Wt[out][in] ----------------
__global__ __launch_bounds__(256) void k_transpose(const float* __restrict__ Wq, const float* __restrict__ Wk,
                                                   const float* __restrict__ Wv, const float* __restrict__ Wo,
                                                   u16* __restrict__ wt){
  const float* src = blockIdx.z==0 ? Wq : blockIdx.z==1 ? Wk : blockIdx.z==2 ? Wv : Wo;
  u16* dst = wt + (size_t)blockIdx.z * CH * CH;
  __shared__ float t[32][33];
  const int x = blockIdx.x*32, y = blockIdx.y*32;
  const int tx = threadIdx.x & 31, ty = threadIdx.x >> 5;
  #pragma unroll
  for (int j=0;j<32;j+=8) t[ty+j][tx] = src[(size_t)(y+ty+j)*CH + x + tx];
  __syncthreads();
  #pragma unroll
  for (int j=0;j<32;j+=8) dst[(size_t)(x+ty+j)*CH + y + tx] = f2bf(t[tx][ty+j]);
}

// ---------------- merged QKV projection GEMM ----------------
__global__ __launch_bounds__(256) void k_gemm_qkv(const float* __restrict__ q, const float* __restrict__ k,
                                                  const float* __restrict__ v, const u16* __restrict__ wt,
                                                  const float* __restrict__ bq, const float* __restrict__ bk,
                                                  const float* __restrict__ bv,
                                                  u16* __restrict__ qh, u16* __restrict__ kh, u16* __restrict__ vt){
  const int z = blockIdx.z;
  const float* A = z==0 ? q : z==1 ? k : v;
  const u16* Bt = wt + (size_t)z*CH*CH;
  const float* bias = z==0 ? bq : z==1 ? bk : bv;
  u16* Cp = z==0 ? qh : z==1 ? kh : vt;
  const float scale = (z==0) ? 0.03125f : 1.0f;

  __shared__ u16 As[64][72];
  __shared__ u16 Bs[64][72];
  const int m0 = blockIdx.y*64, n0 = blockIdx.x*64;
  const int tid = threadIdx.x, lane = tid & 63, w = tid >> 6;
  const int wm = w >> 1, wn = w & 1;
  const int lr = lane & 15, lg = lane >> 4;
  f32x4 acc[2][2] = {};
  for (int k0 = 0; k0 < CH; k0 += 64){
    #pragma unroll
    for (int j=0;j<4;++j){
      int idx = tid + 256*j, r = idx >> 4, c = (idx & 15)*4;
      float4 vv = *(const float4*)&A[(size_t)(m0+r)*CH + k0 + c];
      ushort4 s; s.x=f2bf(vv.x); s.y=f2bf(vv.y); s.z=f2bf(vv.z); s.w=f2bf(vv.w);
      *(ushort4*)&As[r][c] = s;
    }
    #pragma unroll
    for (int j=0;j<2;++j){
      int idx = tid + 256*j, r = idx >> 3, c = (idx & 7)*8;
      *(uint4*)&Bs[r][c] = *(const uint4*)&Bt[(size_t)(n0+r)*CH + k0 + c];
    }
    __syncthreads();
    #pragma unroll
    for (int kk=0; kk<2; ++kk){
      bf16x8 a0 = *(const bf16x8*)&As[wm*32      + lr][kk*32 + lg*8];
      bf16x8 a1 = *(const bf16x8*)&As[wm*32 + 16 + lr][kk*32 + lg*8];
      bf16x8 b0 = *(const bf16x8*)&Bs[wn*32      + lr][kk*32 + lg*8];
      bf16x8 b1 = *(const bf16x8*)&Bs[wn*32 + 16 + lr][kk*32 + lg*8];
      acc[0][0] = __builtin_amdgcn_mfma_f32_16x16x32_bf16(a0,b0,acc[0][0],0,0,0);
      acc[0][1] = __builtin_amdgcn_mfma_f32_16x16x32_bf16(a0,b1,acc[0][1],0,0,0);
      acc[1][0] = __builtin_amdgcn_mfma_f32_16x16x32_bf16(a1,b0,acc[1][0],0,0,0);
      acc[1][1] = __builtin_amdgcn_mfma_f32_16x16x32_bf16(a1,b1,acc[1][1],0,0,0);
    }
    __syncthreads();
  }
  #pragma unroll
  for (int fi=0;fi<2;++fi)
  #pragma unroll
  for (int fj=0;fj<2;++fj)
  #pragma unroll
  for (int r=0;r<4;++r){
    int row = m0 + wm*32 + fi*16 + lg*4 + r;
    int col = n0 + wn*32 + fj*16 + lr;
    float val = (acc[fi][fj][r] + bias[col]) * scale;
    int bb = row >> 11, ll = row & 2047, hh = col >> 6, dd = col & 63;
    if (z < 2){
      Cp[(((size_t)(bb*NH+hh)*QL + ll) << 6) + dd] = f2bf(val);
    } else {
      Cp[(((size_t)(bb*NH+hh) << 6) + dd)*KL + ll] = f2h(val);   // vt in f16 for f16-MFMA PV
    }
  }
}

// ---------------- final projection GEMM: out = ao @ Wo^T + bo (f32 out) ----------------
__global__ __launch_bounds__(256) void k_gemm_out(const u16* __restrict__ Ap, const u16* __restrict__ Bt,
                                                  const float* __restrict__ bias, float* __restrict__ Cp){
  __shared__ u16 As[64][72];
  __shared__ u16 Bs[64][72];
  const int m0 = blockIdx.y*64, n0 = blockIdx.x*64;
  const int tid = threadIdx.x, lane = tid & 63, w = tid >> 6;
  const int wm = w >> 1, wn = w & 1;
  const int lr = lane & 15, lg = lane >> 4;
  f32x4 acc[2][2] = {};
  for (int k0 = 0; k0 < CH; k0 += 64){
    #pragma unroll
    for (int j=0;j<2;++j){
      int idx = tid + 256*j, r = idx >> 3, c = (idx & 7)*8;
      *(uint4*)&As[r][c] = *(const uint4*)&Ap[(size_t)(m0+r)*CH + k0 + c];
      *(uint4*)&Bs[r][c] = *(const uint4*)&Bt[(size_t)(n0+r)*CH + k0 + c];
    }
    __syncthreads();
    #pragma unroll
    for (int kk=0; kk<2; ++kk){
      bf16x8 a0 = *(const bf16x8*)&As[wm*32      + lr][kk*32 + lg*8];
      bf16x8 a1 = *(const bf16x8*)&As[wm*32 + 16 + lr][kk*32 + lg*8];
      bf16x8 b0 = *(const bf16x8*)&Bs[wn*32      + lr][kk*32 + lg*8];
      bf16x8 b1 = *(const bf16x8*)&Bs[wn*32 + 16 + lr][kk*32 + lg*8];
      acc[0][0] = __builtin_amdgcn_mfma_f32_16x16x32_bf16(a0,b0,acc[0][0],0,0,0);
      acc[0][1] = __builtin_amdgcn_mfma_f32_16x16x32_bf16(a0,b1,acc[0][1],0,0,0);
      acc[1][0] = __builtin_amdgcn_mfma_f32_16x16x32_bf16(a1,b0,acc[1][0],0,0,0);
      acc[1][1] = __builtin_amdgcn_mfma_f32_16x16x32_bf16(a1,b1,acc[1][1],0,0,0);
    }
    __syncthreads();
  }
  #pragma unroll
  for (int fi=0;fi<2;++fi)
  #pragma unroll
  for (int fj=0;fj<2;++fj)
  #pragma unroll
  for (int r=0;r<4;++r){
    int row = m0 + wm*32 + fi*16 + lg*4 + r;
    int col = n0 + wn*32 + fj*16 + lr;
    Cp[(size_t)row*CH + col] = acc[fi][fj][r] + bias[col];
  }
}

// ---------------- 2-tile producer-consumer attention (1 block/CU, L2-local K/V) ----------------
// Grid 2048 blocks (64 qt-pairs x 16 h x 2 b); each block runs TPB=2 tiles of 16 q-rows.
// Concurrent 256 blocks span only 4 (h,b) pairs (x-major order) -> kh/vt stay L2-resident
// (the round-13 16-tile version spanned all 32 pairs; 16MB/XCD thrashed L2/L3 -> FETCH 1.48GB).
// Waves 0-7: producers; waves 8-11: attn writers (t-1); waves 12-15: PV (t-1).
__global__ __launch_bounds__(1024, 1) void k_attn_pipe(const u16* __restrict__ qh, const u16* __restrict__ kh,
                                              const _Float16* __restrict__ vt, const float* __restrict__ bias,
                                              const unsigned* __restrict__ mbits,
                                              float* __restrict__ attn, u16* __restrict__ ao){
  __shared__ _Float16 Sh[2][16][PS_STRIDE];   // 133.6 KB
  __shared__ float wsum[2][8][16];            // 1 KB
  const int h = blockIdx.y, b = blockIdx.z;
  const int bh = b*NH + h;
  const int tid = threadIdx.x, lane = tid & 63, w = tid >> 6;  // w 0..15
  const int lr = lane & 15, lg = lane >> 4;
  const u16* khb = kh + (size_t)bh*KL*HD;
  const _Float16* vtb = vt + (size_t)bh*HD*KL;

  for (int it = 0; it <= TPB; ++it){
    __syncthreads();
    if (w < 8){
      if (it < TPB){
        // ---- producer: tile it -> Sh[it&1] ----
        const int qt = blockIdx.x*TPB + it, q0 = qt*16;
        const int buf = it & 1, c0 = w*256;
        const u16* qb = qh + ((size_t)bh*QL + q0)*HD;
        const bf16x8 qf0 = *(const bf16x8*)&qb[lr*HD +      lg*8];
        const bf16x8 qf1 = *(const bf16x8*)&qb[lr*HD + 32 + lg*8];
        const float* bb = bias + ((size_t)bh*QL + q0)*KL;
        float ps = 0.f;
        #pragma unroll
        for (int half=0; half<2; ++half){
          f32x4 bi[8];
          unsigned mwd[8];
          #pragma unroll
          for (int ct=0; ct<8; ++ct){
            const int cb = c0 + half*128 + ct*16 + lg*4;
            bi[ct] = *(const f32x4*)&bb[(size_t)lr*KL + cb];
            mwd[ct] = mbits[((size_t)b*QL + q0 + lr)*(KL/32) + (cb>>5)];
          }
          #pragma unroll
          for (int ct=0; ct<8; ++ct){
            const int cb = c0 + half*128 + ct*16 + lg*4;
            f32x4 acc = bi[ct];
            const int kcol = c0 + half*128 + ct*16 + lr;
            bf16x8 kf0 = *(const bf16x8*)&khb[(size_t)kcol*HD +      lg*8];
            bf16x8 kf1 = *(const bf16x8*)&khb[(size_t)kcol*HD + 32 + lg*8];
            acc = __builtin_amdgcn_mfma_f32_16x16x32_bf16(kf0, qf0, acc, 0,0,0);   // D = S^T frag
            acc = __builtin_amdgcn_mfma_f32_16x16x32_bf16(kf1, qf1, acc, 0,0,0);
            const unsigned msel = (mwd[ct] >> (cb & 31)) & 0xFu;
            f16x4 sv;
            #pragma unroll
            for (int r=0;r<4;++r){
              float e = ((msel >> r) & 1u) ? 0.f : __expf(acc[r]);   // bounded logits
              sv[r] = (_Float16)e;
              ps += e;
            }
            *(f16x4*)&Sh[buf][lr][cb] = sv;
          }
        }
        ps += __shfl_xor(ps, 16);
        ps += __shfl_xor(ps, 32);
        if (lane < 16) wsum[buf][w][lr] = ps;
      }
    } else if (it >= 1){
      // ---- consumer: tile it-1 from Sh[(it-1)&1] ----
      const int t = it - 1;
      const int qt = blockIdx.x*TPB + t, q0 = qt*16;
      const int buf = t & 1;
      if (w < 12){
        // writer wave: 4 rows, normalized f32 attn, 1KB contiguous per instruction
        float* ob = attn + ((size_t)bh*QL + q0)*KL;
        const int r0 = (w - 8)*4;
        #pragma unroll
        for (int rr=0; rr<4; ++rr){
          const int row = r0 + rr;
          float s = 0.f;
          #pragma unroll
          for (int p=0;p<8;++p) s += wsum[buf][p][row];
          const float ivr = 1.f / s;
          float* orow = ob + (size_t)row*KL;
          #pragma unroll
          for (int ch=0; ch<8; ++ch){
            f16x4 hv = *(const f16x4*)&Sh[buf][row][ch*256 + lane*4];
            f32x4 v;
            v[0]=(float)hv[0]*ivr; v[1]=(float)hv[1]*ivr; v[2]=(float)hv[2]*ivr; v[3]=(float)hv[3]*ivr;
            *(f32x4*)&orow[ch*256 + lane*4] = v;
          }
        }
      } else {
        // PV wave: d-strip (w-12)*16, full K; 8-deep batched loads; direct ao write
        const int d0 = (w - 12)*16;
        f32x4 oacc = {};
        #pragma unroll
        for (int kb=0; kb<8; ++kb){
          f16x8 vf[8], af[8];
          #pragma unroll
          for (int i=0;i<8;++i){
            vf[i] = *(const f16x8*)&vtb[(size_t)(d0+lr)*KL + kb*256 + i*32 + lg*8];
            af[i] = *(const f16x8*)&Sh[buf][lr][kb*256 + i*32 + lg*8];
          }
          #pragma unroll
          for (int i=0;i<8;++i)
            oacc = __builtin_amdgcn_mfma_f32_16x16x32_f16(af[i], vf[i], oacc, 0,0,0);
        }
        #pragma unroll
        for (int r=0;r<4;++r){
          const int row = lg*4 + r;        // D: row=(lane>>4)*4+reg (q-row), col=lane&15 (d)
          float s = 0.f;
          #pragma unroll
          for (int p=0;p<8;++p) s += wsum[buf][p][row];
          ao[((size_t)b*QL + q0 + row)*CH + h*HD + d0 + lr] = f2bf(oacc[r] / s);
        }
      }
    }
  }
}

// ---------------- round-9 fused fallback (used when mbits workspace unavailable) ----------------
template<int BITS>
__global__ __launch_bounds__(1024, 1) void k_attn(const u16* __restrict__ qh, const u16* __restrict__ kh,
                                              const _Float16* __restrict__ vt, const float* __restrict__ bias,
                                              const void* __restrict__ maskp, const int* __restrict__ flag,
                                              const unsigned* __restrict__ mbits,
                                              float* __restrict__ attn, u16* __restrict__ ao){
  __shared__ _Float16 Sh[16][SH_STRIDE];
  __shared__ float osum[8][16][17];
  __shared__ float wsum[16][16];
  __shared__ float inv_l[16];
  const int qt = BITS ? blockIdx.x : blockIdx.y;
  const int h  = BITS ? blockIdx.y : blockIdx.x;
  const int b  = blockIdx.z;
  const int q0 = qt*16, bh = b*NH + h;
  const int tid = threadIdx.x, lane = tid & 63, w = tid >> 6;
  const int lr = lane & 15, lg = lane >> 4;
  const u16* qb = qh + ((size_t)bh*QL + q0)*HD;
  const bf16x8 qf0 = *(const bf16x8*)&qb[lr*HD +      lg*8];
  const bf16x8 qf1 = *(const bf16x8*)&qb[lr*HD + 32 + lg*8];
  const float* bb = bias + ((size_t)bh*QL + q0)*KL;
  const u16* khb = kh + (size_t)bh*KL*HD;
  const _Float16* vtb = vt + (size_t)bh*HD*KL;
  const int c0 = w*128;

  f32x4 bi[8];
  unsigned mwd[8];
  #pragma unroll
  for (int ct=0; ct<8; ++ct){
    const int cb = c0 + ct*16 + lg*4;
    bi[ct] = *(const f32x4*)&bb[(size_t)lr*KL + cb];
    if (BITS) mwd[ct] = mbits[((size_t)b*QL + q0 + lr)*(KL/32) + (cb>>5)];
  }
  const int isbool = BITS ? 0 : *flag;
  const unsigned char* mb8 = (const unsigned char*)maskp + ((size_t)b*QL + q0)*KL;
  const int* mb32 = (const int*)maskp + ((size_t)b*QL + q0)*KL;

  float ps = 0.f;
  #pragma unroll
  for (int ct=0; ct<8; ++ct){
    const int cb = c0 + ct*16 + lg*4;
    f32x4 acc = bi[ct];
    const int kcol = c0 + ct*16 + lr;
    bf16x8 kf0 = *(const bf16x8*)&khb[(size_t)kcol*HD +      lg*8];
    bf16x8 kf1 = *(const bf16x8*)&khb[(size_t)kcol*HD + 32 + lg*8];
    acc = __builtin_amdgcn_mfma_f32_16x16x32_bf16(kf0, qf0, acc, 0,0,0);
    acc = __builtin_amdgcn_mfma_f32_16x16x32_bf16(kf1, qf1, acc, 0,0,0);
    unsigned msel;
    i32x4 mv;
    if (BITS){
      msel = (mwd[ct] >> (cb & 31)) & 0xFu;
    } else if (isbool){
      unsigned mw = *(const unsigned*)&mb8[(size_t)lr*KL + cb];
      msel = (mw&1u) | ((mw>>7)&2u) | ((mw>>14)&4u) | ((mw>>21)&8u);
    } else {
      mv = *(const i32x4*)&mb32[(size_t)lr*KL + cb];
      msel = (unsigned)((mv[0]&1) | ((mv[1]&1)<<1) | ((mv[2]&1)<<2) | ((mv[3]&1)<<3));
    }
    f16x4 sv;
    #pragma unroll
    for (int r=0;r<4;++r){
      float e = ((msel >> r) & 1u) ? 0.f : __expf(acc[r]);
      sv[r] = (_Float16)e;
      ps += e;
    }
    *(f16x4*)&Sh[lr][cb] = sv;
  }
  ps += __shfl_xor(ps, 16);
  ps += __shfl_xor(ps, 32);
  if (lane < 16) wsum[w][lr] = ps;
  __syncthreads();
  if (tid < 16){
    float s = 0.f;
    #pragma unroll
    for (int ww=0; ww<16; ++ww) s += wsum[ww][tid];
    inv_l[tid] = 1.f / s;
  }
  __syncthreads();

  if (w < 8){
    const int d0 = (w & 3)*16, kb0 = (w >> 2)*1024;
    f32x4 oacc = {};
    #pragma unroll
    for (int kb=0; kb<4; ++kb){
      f16x8 vf[8];
      #pragma unroll
      for (int i=0;i<8;++i)
        vf[i] = *(const f16x8*)&vtb[(size_t)(d0+lr)*KL + kb0 + kb*256 + i*32 + lg*8];
      #pragma unroll
      for (int i=0;i<8;++i){
        f16x8 a = *(const f16x8*)&Sh[lr][kb0 + kb*256 + i*32 + lg*8];
        oacc = __builtin_amdgcn_mfma_f32_16x16x32_f16(a, vf[i], oacc, 0,0,0);
      }
    }
    #pragma unroll
    for (int r=0;r<4;++r) osum[w][lg*4+r][lr] = oacc[r];
  } else {
    float* ob = attn + ((size_t)bh*QL + q0)*KL;
    const int r0 = (w - 8)*2;
    #pragma unroll
    for (int rr=0; rr<2; ++rr){
      const int row = r0 + rr;
      const float ivr = inv_l[row];
      #pragma unroll
      for (int ch=0; ch<8; ++ch){
        f16x4 hv = *(const f16x4*)&Sh[row][ch*256 + lane*4];
        f32x4 v;
        v[0]=(float)hv[0]*ivr; v[1]=(float)hv[1]*ivr; v[2]=(float)hv[2]*ivr; v[3]=(float)hv[3]*ivr;
        *(f32x4*)&ob[(size_t)row*KL + ch*256 + lane*4] = v;
      }
    }
  }
  __syncthreads();
  {
    const int row = tid >> 6, d = tid & 63;
    float o = (osum[d >> 4][row][d & 15] + osum[4 + (d >> 4)][row][d & 15]) * inv_l[row];
    ao[((size_t)b*QL + q0 + row)*CH + h*HD + d] = f2bf(o);
  }
}

extern "C" void kernel_launch(void* const* d_in, const int* in_sizes, int n_in,
                              void* d_out, int out_size, void* d_ws, size_t ws_size,
                              hipStream_t stream){
  const float* q    = (const float*)d_in[0];
  const float* k    = (const float*)d_in[1];
  const float* v    = (const float*)d_in[2];
  const void*  mask = d_in[3];
  const float* bias = (const float*)d_in[4];
  const float* Wq   = (const float*)d_in[5];
  const float* bq   = (const float*)d_in[6];
  const float* Wk   = (const float*)d_in[7];
  const float* bk   = (const float*)d_in[8];
  const float* Wv   = (const float*)d_in[9];
  const float* bv   = (const float*)d_in[10];
  const float* Wo   = (const float*)d_in[11];
  const float* bo   = (const float*)d_in[12];

  char* wsb = (char*)d_ws;
  int* flag = (int*)wsb;
  u16* qh = (u16*)(wsb + 256);
  u16* kh = (u16*)(wsb + 256 + 1*8388608);
  u16* vt = (u16*)(wsb + 256 + 2*8388608);
  u16* ao = (u16*)(wsb + 256 + 3*8388608);
  u16* wt = (u16*)(wsb + 256 + 4*8388608);
  unsigned* mbits = (unsigned*)(wsb + 256 + 5*8388608);
  const size_t need_bits = 256 + 5ull*8388608 + 1048576;
  const bool usebits = (ws_size >= need_bits);

  float* out  = (float*)d_out;
  float* attn = out + (size_t)NB*QL*CH;

  k_detect<<<1, 256, 0, stream>>>((const unsigned int*)mask, flag);
  if (usebits)
    k_maskpack<<<dim3(1024), 256, 0, stream>>>(mask, flag, mbits);
  k_transpose<<<dim3(32,32,4), 256, 0, stream>>>(Wq, Wk, Wv, Wo, wt);
  k_gemm_qkv<<<dim3(16,64,3), 256, 0, stream>>>(q, k, v, wt, bq, bk, bv, qh, kh, vt);
  if (usebits)
    k_attn_pipe<<<dim3(64,16,2), 1024, 0, stream>>>(qh, kh, (const _Float16*)vt, bias, mbits, attn, ao);
  else
    k_attn<0><<<dim3(16,128,2), 1024, 0, stream>>>(qh, kh, (const _Float16*)vt, bias, mask, flag, mbits, attn, ao);
  k_gemm_out<<<dim3(16,64), 256, 0, stream>>>(ao, wt + 3145728, bo, out);
}

// Round 15
// 567.844 us; speedup vs baseline: 1.3489x; 1.1580x over previous
//
#include <hip/hip_runtime.h>
#include <hip/hip_bf16.h>

// MultiHeadAttention fused pipeline for MI355X (gfx950).
// Outputs: [0] out (2*2048*1024 f32), [1] attn (2*16*2048*2048 f32), concatenated in d_out.
// ws layout: [flag:256B][qh 8MB][kh 8MB][vt 8MB][ao 8MB][wt 8MB][mbits 1MB][qc 8][kc 8][vc 8] = ~66MB.

typedef __attribute__((ext_vector_type(8))) short bf16x8;
typedef __attribute__((ext_vector_type(8))) _Float16 f16x8;
typedef __attribute__((ext_vector_type(4))) float f32x4;
typedef __attribute__((ext_vector_type(4))) int i32x4;
typedef __attribute__((ext_vector_type(4))) _Float16 f16x4;
typedef unsigned short u16;

#define NB 2
#define QL 2048
#define KL 2048
#define CH 1024
#define NH 16
#define HD 64
#define SH_STRIDE 2600   // fused attn Sh stride (~83KB -> 1 block/CU clean-write regime)

__device__ __forceinline__ u16 f2bf(float f){
  unsigned u = __float_as_uint(f);
  u += 0x7fffu + ((u >> 16) & 1u);   // RNE
  return (u16)(u >> 16);
}
__device__ __forceinline__ u16 f2h(float f){
  _Float16 h = (_Float16)f;
  return *(u16*)&h;
}

// ---------------- mask dtype detector: int32 0/1 vs packed bool bytes ----------------
__global__ void k_detect(const unsigned int* __restrict__ m, int* __restrict__ flag){
  unsigned v = m[threadIdx.x];
  unsigned long long b = __ballot(v > 1u);
  __shared__ int r[4];
  if ((threadIdx.x & 63) == 0) r[threadIdx.x >> 6] = (b != 0ULL);
  __syncthreads();
  if (threadIdx.x == 0) *flag = (r[0] | r[1] | r[2] | r[3]);
}

// ---------------- mask -> 1 bit/elem (1MB; L2/L3-resident) ----------------
__global__ __launch_bounds__(256) void k_maskpack(const void* __restrict__ maskp, const int* __restrict__ flag,
                                                  unsigned* __restrict__ mbits){
  const int idx = blockIdx.x*256 + threadIdx.x;
  unsigned out = 0;
  if (*flag){
    const unsigned* m8 = (const unsigned*)maskp + (size_t)idx*8;
    #pragma unroll
    for (int j=0;j<8;++j){
      unsigned wv = m8[j];
      out |= ((wv & 1u) | ((wv>>7)&2u) | ((wv>>14)&4u) | ((wv>>21)&8u)) << (4*j);
    }
  } else {
    const i32x4* m32 = (const i32x4*)maskp + (size_t)idx*8;
    #pragma unroll
    for (int j=0;j<8;++j){
      i32x4 v = m32[j];
      out |= (unsigned)((v[0]&1) | ((v[1]&1)<<1) | ((v[2]&1)<<2) | ((v[3]&1)<<3)) << (4*j);
    }
  }
  mbits[idx] = out;
}

// ---------------- f32 -> bf16 pre-convert for q,k,v (z selects stream) ----------------
__global__ __launch_bounds__(256) void k_cvt(const float* __restrict__ q, const float* __restrict__ k,
                                             const float* __restrict__ v,
                                             u16* __restrict__ qc, u16* __restrict__ kc, u16* __restrict__ vc){
  const float* in = blockIdx.y==0 ? q : blockIdx.y==1 ? k : v;
  u16* out = blockIdx.y==0 ? qc : blockIdx.y==1 ? kc : vc;
  const size_t i = ((size_t)blockIdx.x*256 + threadIdx.x)*8;
  float4 lo = *(const float4*)&in[i];
  float4 hi = *(const float4*)&in[i+4];
  ushort4 a, b;
  a.x=f2bf(lo.x); a.y=f2bf(lo.y); a.z=f2bf(lo.z); a.w=f2bf(lo.w);
  b.x=f2bf(hi.x); b.y=f2bf(hi.y); b.z=f2bf(hi.z); b.w=f2bf(hi.w);
  *(ushort4*)&out[i] = a;
  *(ushort4*)&out[i+4] = b;
}

// ---------------- weight transpose + bf16 convert: W[in][out] -> Wt[out][in] ----------------
__global__ __launch_bounds__(256) void k_transpose(const float* __restrict__ Wq, const float* __restrict__ Wk,
                                                   const float* __restrict__ Wv, const float* __restrict__ Wo,
                                                   u16* __restrict__ wt){
  const float* src = blockIdx.z==0 ? Wq : blockIdx.z==1 ? Wk : blockIdx.z==2 ? Wv : Wo;
  u16* dst = wt + (size_t)blockIdx.z * CH * CH;
  __shared__ float t[32][33];
  const int x = blockIdx.x*32, y = blockIdx.y*32;
  const int tx = threadIdx.x & 31, ty = threadIdx.x >> 5;
  #pragma unroll
  for (int j=0;j<32;j+=8) t[ty+j][tx] = src[(size_t)(y+ty+j)*CH + x + tx];
  __syncthreads();
  #pragma unroll
  for (int j=0;j<32;j+=8) dst[(size_t)(x+ty+j)*CH + y + tx] = f2bf(t[tx][ty+j]);
}

// ---------------- swizzled bf16 GEMM, 64^2 tile, light staging ----------------
// A [M][CH] bf16, Bt [N][CH] bf16 (pre-transposed). LDS chunk-XOR swizzle (chunk^=row&7)
// on stage-write and frag-read: conflict-free-ish ds_read_b128, 1 load+1 store staging/thread.
// clay: 0 = qh/kh bf16 scatter (scaled), 1 = vt f16 scatter, 2 = f32 + bias (plain MxCH)
__device__ __forceinline__ void gemm64_body(const u16* __restrict__ A, const u16* __restrict__ Bt,
                                            const float* __restrict__ bias, void* __restrict__ Cp,
                                            int clay, float scale, int m0, int n0){
  __shared__ u16 As[64][64];
  __shared__ u16 Bs[64][64];
  const int tid = threadIdx.x, lane = tid & 63, w = tid >> 6;
  const int wm = w >> 1, wn = w & 1;
  const int lr = lane & 15, lg = lane >> 4;
  f32x4 acc[2][2] = {};
  for (int k0 = 0; k0 < CH; k0 += 64){
    #pragma unroll
    for (int i=0;i<2;++i){
      const int r = i*32 + (tid>>3), c8 = tid & 7;
      const int sw = (c8 ^ (r&7))*8;
      *(uint4*)&As[r][sw] = *(const uint4*)&A[(size_t)(m0+r)*CH + k0 + c8*8];
      *(uint4*)&Bs[r][sw] = *(const uint4*)&Bt[(size_t)(n0+r)*CH + k0 + c8*8];
    }
    __syncthreads();
    #pragma unroll
    for (int kk=0; kk<2; ++kk){
      const int c8a = ((kk*4 + lg) ^ (lr&7))*8;
      bf16x8 a0 = *(const bf16x8*)&As[wm*32      + lr][c8a];
      bf16x8 a1 = *(const bf16x8*)&As[wm*32 + 16 + lr][c8a];
      bf16x8 b0 = *(const bf16x8*)&Bs[wn*32      + lr][c8a];
      bf16x8 b1 = *(const bf16x8*)&Bs[wn*32 + 16 + lr][c8a];
      acc[0][0] = __builtin_amdgcn_mfma_f32_16x16x32_bf16(a0,b0,acc[0][0],0,0,0);
      acc[0][1] = __builtin_amdgcn_mfma_f32_16x16x32_bf16(a0,b1,acc[0][1],0,0,0);
      acc[1][0] = __builtin_amdgcn_mfma_f32_16x16x32_bf16(a1,b0,acc[1][0],0,0,0);
      acc[1][1] = __builtin_amdgcn_mfma_f32_16x16x32_bf16(a1,b1,acc[1][1],0,0,0);
    }
    __syncthreads();
  }
  #pragma unroll
  for (int fi=0;fi<2;++fi)
  #pragma unroll
  for (int fj=0;fj<2;++fj)
  #pragma unroll
  for (int r=0;r<4;++r){
    int row = m0 + wm*32 + fi*16 + lg*4 + r;   // C/D: col=lane&15, row=(lane>>4)*4+reg
    int col = n0 + wn*32 + fj*16 + lr;
    float val = (acc[fi][fj][r] + bias[col]) * scale;
    if (clay == 2){
      ((float*)Cp)[(size_t)row*CH + col] = val;
    } else {
      int bb = row >> 11, ll = row & 2047, hh = col >> 6, dd = col & 63;
      if (clay == 0)
        ((u16*)Cp)[(((size_t)(bb*NH+hh)*QL + ll) << 6) + dd] = f2bf(val);
      else
        ((u16*)Cp)[(((size_t)(bb*NH+hh) << 6) + dd)*KL + ll] = f2h(val);
    }
  }
}

__global__ __launch_bounds__(256) void k_gemm_qkv2(const u16* __restrict__ qc, const u16* __restrict__ kc,
                                                   const u16* __restrict__ vc, const u16* __restrict__ wt,
                                                   const float* __restrict__ bq, const float* __restrict__ bk,
                                                   const float* __restrict__ bv,
                                                   u16* __restrict__ qh, u16* __restrict__ kh, u16* __restrict__ vt){
  const int z = blockIdx.z;
  const u16* A = z==0 ? qc : z==1 ? kc : vc;
  const u16* Bt = wt + (size_t)z*CH*CH;
  const float* bias = z==0 ? bq : z==1 ? bk : bv;
  void* Cp = z==0 ? (void*)qh : z==1 ? (void*)kh : (void*)vt;
  gemm64_body(A, Bt, bias, Cp, z==2 ? 1 : 0, z==0 ? 0.03125f : 1.0f, blockIdx.y*64, blockIdx.x*64);
}

__global__ __launch_bounds__(256) void k_gemm_out2(const u16* __restrict__ ao, const u16* __restrict__ wto,
                                                   const float* __restrict__ bo, float* __restrict__ out){
  gemm64_body(ao, wto, bo, out, 2, 1.0f, blockIdx.y*64, blockIdx.x*64);
}

// ---------------- legacy projection GEMMs (fallback when ws too small for bf16 copies) ----------------
__global__ __launch_bounds__(256) void k_gemm_qkv(const float* __restrict__ q, const float* __restrict__ k,
                                                  const float* __restrict__ v, const u16* __restrict__ wt,
                                                  const float* __restrict__ bq, const float* __restrict__ bk,
                                                  const float* __restrict__ bv,
                                                  u16* __restrict__ qh, u16* __restrict__ kh, u16* __restrict__ vt){
  const int z = blockIdx.z;
  const float* A = z==0 ? q : z==1 ? k : v;
  const u16* Bt = wt + (size_t)z*CH*CH;
  const float* bias = z==0 ? bq : z==1 ? bk : bv;
  u16* Cp = z==0 ? qh : z==1 ? kh : vt;
  const float scale = (z==0) ? 0.03125f : 1.0f;
  __shared__ u16 As[64][72];
  __shared__ u16 Bs[64][72];
  const int m0 = blockIdx.y*64, n0 = blockIdx.x*64;
  const int tid = threadIdx.x, lane = tid & 63, w = tid >> 6;
  const int wm = w >> 1, wn = w & 1;
  const int lr = lane & 15, lg = lane >> 4;
  f32x4 acc[2][2] = {};
  for (int k0 = 0; k0 < CH; k0 += 64){
    #pragma unroll
    for (int j=0;j<4;++j){
      int idx = tid + 256*j, r = idx >> 4, c = (idx & 15)*4;
      float4 vv = *(const float4*)&A[(size_t)(m0+r)*CH + k0 + c];
      ushort4 s; s.x=f2bf(vv.x); s.y=f2bf(vv.y); s.z=f2bf(vv.z); s.w=f2bf(vv.w);
      *(ushort4*)&As[r][c] = s;
    }
    #pragma unroll
    for (int j=0;j<2;++j){
      int idx = tid + 256*j, r = idx >> 3, c = (idx & 7)*8;
      *(uint4*)&Bs[r][c] = *(const uint4*)&Bt[(size_t)(n0+r)*CH + k0 + c];
    }
    __syncthreads();
    #pragma unroll
    for (int kk=0; kk<2; ++kk){
      bf16x8 a0 = *(const bf16x8*)&As[wm*32      + lr][kk*32 + lg*8];
      bf16x8 a1 = *(const bf16x8*)&As[wm*32 + 16 + lr][kk*32 + lg*8];
      bf16x8 b0 = *(const bf16x8*)&Bs[wn*32      + lr][kk*32 + lg*8];
      bf16x8 b1 = *(const bf16x8*)&Bs[wn*32 + 16 + lr][kk*32 + lg*8];
      acc[0][0] = __builtin_amdgcn_mfma_f32_16x16x32_bf16(a0,b0,acc[0][0],0,0,0);
      acc[0][1] = __builtin_amdgcn_mfma_f32_16x16x32_bf16(a0,b1,acc[0][1],0,0,0);
      acc[1][0] = __builtin_amdgcn_mfma_f32_16x16x32_bf16(a1,b0,acc[1][0],0,0,0);
      acc[1][1] = __builtin_amdgcn_mfma_f32_16x16x32_bf16(a1,b1,acc[1][1],0,0,0);
    }
    __syncthreads();
  }
  #pragma unroll
  for (int fi=0;fi<2;++fi)
  #pragma unroll
  for (int fj=0;fj<2;++fj)
  #pragma unroll
  for (int r=0;r<4;++r){
    int row = m0 + wm*32 + fi*16 + lg*4 + r;
    int col = n0 + wn*32 + fj*16 + lr;
    float val = (acc[fi][fj][r] + bias[col]) * scale;
    int bb = row >> 11, ll = row & 2047, hh = col >> 6, dd = col & 63;
    if (z < 2) Cp[(((size_t)(bb*NH+hh)*QL + ll) << 6) + dd] = f2bf(val);
    else       Cp[(((size_t)(bb*NH+hh) << 6) + dd)*KL + ll] = f2h(val);
  }
}

__global__ __launch_bounds__(256) void k_gemm_out(const u16* __restrict__ Ap, const u16* __restrict__ Bt,
                                                  const float* __restrict__ bias, float* __restrict__ Cp){
  __shared__ u16 As[64][72];
  __shared__ u16 Bs[64][72];
  const int m0 = blockIdx.y*64, n0 = blockIdx.x*64;
  const int tid = threadIdx.x, lane = tid & 63, w = tid >> 6;
  const int wm = w >> 1, wn = w & 1;
  const int lr = lane & 15, lg = lane >> 4;
  f32x4 acc[2][2] = {};
  for (int k0 = 0; k0 < CH; k0 += 64){
    #pragma unroll
    for (int j=0;j<2;++j){
      int idx = tid + 256*j, r = idx >> 3, c = (idx & 7)*8;
      *(uint4*)&As[r][c] = *(const uint4*)&Ap[(size_t)(m0+r)*CH + k0 + c];
      *(uint4*)&Bs[r][c] = *(const uint4*)&Bt[(size_t)(n0+r)*CH + k0 + c];
    }
    __syncthreads();
    #pragma unroll
    for (int kk=0; kk<2; ++kk){
      bf16x8 a0 = *(const bf16x8*)&As[wm*32      + lr][kk*32 + lg*8];
      bf16x8 a1 = *(const bf16x8*)&As[wm*32 + 16 + lr][kk*32 + lg*8];
      bf16x8 b0 = *(const bf16x8*)&Bs[wn*32      + lr][kk*32 + lg*8];
      bf16x8 b1 = *(const bf16x8*)&Bs[wn*32 + 16 + lr][kk*32 + lg*8];
      acc[0][0] = __builtin_amdgcn_mfma_f32_16x16x32_bf16(a0,b0,acc[0][0],0,0,0);
      acc[0][1] = __builtin_amdgcn_mfma_f32_16x16x32_bf16(a0,b1,acc[0][1],0,0,0);
      acc[1][0] = __builtin_amdgcn_mfma_f32_16x16x32_bf16(a1,b0,acc[1][0],0,0,0);
      acc[1][1] = __builtin_amdgcn_mfma_f32_16x16x32_bf16(a1,b1,acc[1][1],0,0,0);
    }
    __syncthreads();
  }
  #pragma unroll
  for (int fi=0;fi<2;++fi)
  #pragma unroll
  for (int fj=0;fj<2;++fj)
  #pragma unroll
  for (int r=0;r<4;++r){
    int row = m0 + wm*32 + fi*16 + lg*4 + r;
    int col = n0 + wn*32 + fj*16 + lr;
    Cp[(size_t)row*CH + col] = acc[fi][fj][r] + bias[col];
  }
}

// ---------------- fused attention (round-9 structure: best measured, clean writes) ----------------
template<int BITS>
__global__ __launch_bounds__(1024, 1) void k_attn(const u16* __restrict__ qh, const u16* __restrict__ kh,
                                              const _Float16* __restrict__ vt, const float* __restrict__ bias,
                                              const void* __restrict__ maskp, const int* __restrict__ flag,
                                              const unsigned* __restrict__ mbits,
                                              float* __restrict__ attn, u16* __restrict__ ao){
  __shared__ _Float16 Sh[16][SH_STRIDE];
  __shared__ float osum[8][16][17];
  __shared__ float wsum[16][16];
  __shared__ float inv_l[16];
  const int qt = BITS ? blockIdx.x : blockIdx.y;
  const int h  = BITS ? blockIdx.y : blockIdx.x;
  const int b  = blockIdx.z;
  const int q0 = qt*16, bh = b*NH + h;
  const int tid = threadIdx.x, lane = tid & 63, w = tid >> 6;
  const int lr = lane & 15, lg = lane >> 4;
  const u16* qb = qh + ((size_t)bh*QL + q0)*HD;
  const bf16x8 qf0 = *(const bf16x8*)&qb[lr*HD +      lg*8];
  const bf16x8 qf1 = *(const bf16x8*)&qb[lr*HD + 32 + lg*8];
  const float* bb = bias + ((size_t)bh*QL + q0)*KL;
  const u16* khb = kh + (size_t)bh*KL*HD;
  const _Float16* vtb = vt + (size_t)bh*HD*KL;
  const int c0 = w*128;

  f32x4 bi[8];
  unsigned mwd[8];
  #pragma unroll
  for (int ct=0; ct<8; ++ct){
    const int cb = c0 + ct*16 + lg*4;
    bi[ct] = *(const f32x4*)&bb[(size_t)lr*KL + cb];
    if (BITS) mwd[ct] = mbits[((size_t)b*QL + q0 + lr)*(KL/32) + (cb>>5)];
  }
  const int isbool = BITS ? 0 : *flag;
  const unsigned char* mb8 = (const unsigned char*)maskp + ((size_t)b*QL + q0)*KL;
  const int* mb32 = (const int*)maskp + ((size_t)b*QL + q0)*KL;

  float ps = 0.f;
  #pragma unroll
  for (int ct=0; ct<8; ++ct){
    const int cb = c0 + ct*16 + lg*4;
    f32x4 acc = bi[ct];
    const int kcol = c0 + ct*16 + lr;
    bf16x8 kf0 = *(const bf16x8*)&khb[(size_t)kcol*HD +      lg*8];
    bf16x8 kf1 = *(const bf16x8*)&khb[(size_t)kcol*HD + 32 + lg*8];
    acc = __builtin_amdgcn_mfma_f32_16x16x32_bf16(kf0, qf0, acc, 0,0,0);   // swapped: D = S^T frag
    acc = __builtin_amdgcn_mfma_f32_16x16x32_bf16(kf1, qf1, acc, 0,0,0);
    unsigned msel;
    i32x4 mv;
    if (BITS){
      msel = (mwd[ct] >> (cb & 31)) & 0xFu;
    } else if (isbool){
      unsigned mw = *(const unsigned*)&mb8[(size_t)lr*KL + cb];
      msel = (mw&1u) | ((mw>>7)&2u) | ((mw>>14)&4u) | ((mw>>21)&8u);
    } else {
      mv = *(const i32x4*)&mb32[(size_t)lr*KL + cb];
      msel = (unsigned)((mv[0]&1) | ((mv[1]&1)<<1) | ((mv[2]&1)<<2) | ((mv[3]&1)<<3));
    }
    f16x4 sv;
    #pragma unroll
    for (int r=0;r<4;++r){
      float e = ((msel >> r) & 1u) ? 0.f : __expf(acc[r]);   // bounded logits: no max-sub
      sv[r] = (_Float16)e;
      ps += e;
    }
    *(f16x4*)&Sh[lr][cb] = sv;
  }
  ps += __shfl_xor(ps, 16);
  ps += __shfl_xor(ps, 32);
  if (lane < 16) wsum[w][lr] = ps;
  __syncthreads();
  if (tid < 16){
    float s = 0.f;
    #pragma unroll
    for (int ww=0; ww<16; ++ww) s += wsum[ww][tid];
    inv_l[tid] = 1.f / s;
  }
  __syncthreads();

  if (w < 8){
    const int d0 = (w & 3)*16, kb0 = (w >> 2)*1024;
    f32x4 oacc = {};
    #pragma unroll
    for (int kb=0; kb<4; ++kb){
      f16x8 vf[8];
      #pragma unroll
      for (int i=0;i<8;++i)
        vf[i] = *(const f16x8*)&vtb[(size_t)(d0+lr)*KL + kb0 + kb*256 + i*32 + lg*8];
      #pragma unroll
      for (int i=0;i<8;++i){
        f16x8 a = *(const f16x8*)&Sh[lr][kb0 + kb*256 + i*32 + lg*8];
        oacc = __builtin_amdgcn_mfma_f32_16x16x32_f16(a, vf[i], oacc, 0,0,0);
      }
    }
    #pragma unroll
    for (int r=0;r<4;++r) osum[w][lg*4+r][lr] = oacc[r];
  } else {
    float* ob = attn + ((size_t)bh*QL + q0)*KL;
    const int r0 = (w - 8)*2;
    #pragma unroll
    for (int rr=0; rr<2; ++rr){
      const int row = r0 + rr;
      const float ivr = inv_l[row];
      #pragma unroll
      for (int ch=0; ch<8; ++ch){
        f16x4 hv = *(const f16x4*)&Sh[row][ch*256 + lane*4];
        f32x4 v;
        v[0]=(float)hv[0]*ivr; v[1]=(float)hv[1]*ivr; v[2]=(float)hv[2]*ivr; v[3]=(float)hv[3]*ivr;
        *(f32x4*)&ob[(size_t)row*KL + ch*256 + lane*4] = v;
      }
    }
  }
  __syncthreads();
  {
    const int row = tid >> 6, d = tid & 63;
    float o = (osum[d >> 4][row][d & 15] + osum[4 + (d >> 4)][row][d & 15]) * inv_l[row];
    ao[((size_t)b*QL + q0 + row)*CH + h*HD + d] = f2bf(o);
  }
}

extern "C" void kernel_launch(void* const* d_in, const int* in_sizes, int n_in,
                              void* d_out, int out_size, void* d_ws, size_t ws_size,
                              hipStream_t stream){
  const float* q    = (const float*)d_in[0];
  const float* k    = (const float*)d_in[1];
  const float* v    = (const float*)d_in[2];
  const void*  mask = d_in[3];
  const float* bias = (const float*)d_in[4];
  const float* Wq   = (const float*)d_in[5];
  const float* bq   = (const float*)d_in[6];
  const float* Wk   = (const float*)d_in[7];
  const float* bk   = (const float*)d_in[8];
  const float* Wv   = (const float*)d_in[9];
  const float* bv   = (const float*)d_in[10];
  const float* Wo   = (const float*)d_in[11];
  const float* bo   = (const float*)d_in[12];

  char* wsb = (char*)d_ws;
  int* flag = (int*)wsb;
  u16* qh = (u16*)(wsb + 256);
  u16* kh = (u16*)(wsb + 256 + 1*8388608);
  u16* vt = (u16*)(wsb + 256 + 2*8388608);
  u16* ao = (u16*)(wsb + 256 + 3*8388608);
  u16* wt = (u16*)(wsb + 256 + 4*8388608);
  unsigned* mbits = (unsigned*)(wsb + 256 + 5*8388608);
  u16* qc = (u16*)(wsb + 256 + 5*8388608 + 1048576);
  u16* kc = qc + (size_t)NB*QL*CH;
  u16* vc = kc + (size_t)NB*QL*CH;
  const size_t need_bits = 256 + 5ull*8388608 + 1048576;
  const size_t need_conv = need_bits + 3ull*NB*QL*CH*2;
  const bool usebits = (ws_size >= need_bits);
  const bool useconv = (ws_size >= need_conv);

  float* out  = (float*)d_out;
  float* attn = out + (size_t)NB*QL*CH;

  k_detect<<<1, 256, 0, stream>>>((const unsigned int*)mask, flag);
  if (usebits)
    k_maskpack<<<dim3(1024), 256, 0, stream>>>(mask, flag, mbits);
  k_transpose<<<dim3(32,32,4), 256, 0, stream>>>(Wq, Wk, Wv, Wo, wt);
  if (useconv){
    k_cvt<<<dim3(2048,3), 256, 0, stream>>>(q, k, v, qc, kc, vc);
    k_gemm_qkv2<<<dim3(16,64,3), 256, 0, stream>>>(qc, kc, vc, wt, bq, bk, bv, qh, kh, vt);
  } else {
    k_gemm_qkv<<<dim3(16,64,3), 256, 0, stream>>>(q, k, v, wt, bq, bk, bv, qh, kh, vt);
  }
  if (usebits)
    k_attn<1><<<dim3(128,16,2), 1024, 0, stream>>>(qh, kh, (const _Float16*)vt, bias, mask, flag, mbits, attn, ao);
  else
    k_attn<0><<<dim3(16,128,2), 1024, 0, stream>>>(qh, kh, (const _Float16*)vt, bias, mask, flag, mbits, attn, ao);
  if (useconv)
    k_gemm_out2<<<dim3(16,64), 256, 0, stream>>>(ao, wt + 3145728, bo, out);
  else
    k_gemm_out<<<dim3(16,64), 256, 0, stream>>>(ao, wt + 3145728, bo, out);
}

// Round 16
// 554.752 us; speedup vs baseline: 1.3808x; 1.0236x over previous
//
#include <hip/hip_runtime.h>
#include <hip/hip_bf16.h>

// MultiHeadAttention fused pipeline for MI355X (gfx950).
// Outputs: [0] out (2*2048*1024 f32), [1] attn (2*16*2048*2048 f32), concatenated in d_out.
// ws layout: [flag:256B][qh 8MB][kh 8MB][vt 8MB][ao 8MB][wt 8MB][mbits 1MB][qc 8][kc 8][vc 8] = ~66MB.

typedef __attribute__((ext_vector_type(8))) short bf16x8;
typedef __attribute__((ext_vector_type(8))) _Float16 f16x8;
typedef __attribute__((ext_vector_type(4))) float f32x4;
typedef __attribute__((ext_vector_type(4))) int i32x4;
typedef __attribute__((ext_vector_type(4))) _Float16 f16x4;
typedef unsigned short u16;

#define NB 2
#define QL 2048
#define KL 2048
#define CH 1024
#define NH 16
#define HD 64
#define SH_STRIDE 2600   // fused attn Sh stride (~83KB -> 1 block/CU clean-write regime)

__device__ __forceinline__ u16 f2bf(float f){
  unsigned u = __float_as_uint(f);
  u += 0x7fffu + ((u >> 16) & 1u);   // RNE
  return (u16)(u >> 16);
}
__device__ __forceinline__ u16 f2h(float f){
  _Float16 h = (_Float16)f;
  return *(u16*)&h;
}

// ---------------- mask dtype detector: int32 0/1 vs packed bool bytes ----------------
__global__ void k_detect(const unsigned int* __restrict__ m, int* __restrict__ flag){
  unsigned v = m[threadIdx.x];
  unsigned long long b = __ballot(v > 1u);
  __shared__ int r[4];
  if ((threadIdx.x & 63) == 0) r[threadIdx.x >> 6] = (b != 0ULL);
  __syncthreads();
  if (threadIdx.x == 0) *flag = (r[0] | r[1] | r[2] | r[3]);
}

// ---------------- mask -> 1 bit/elem (1MB; L2/L3-resident) ----------------
__global__ __launch_bounds__(256) void k_maskpack(const void* __restrict__ maskp, const int* __restrict__ flag,
                                                  unsigned* __restrict__ mbits){
  const int idx = blockIdx.x*256 + threadIdx.x;
  unsigned out = 0;
  if (*flag){
    const unsigned* m8 = (const unsigned*)maskp + (size_t)idx*8;
    #pragma unroll
    for (int j=0;j<8;++j){
      unsigned wv = m8[j];
      out |= ((wv & 1u) | ((wv>>7)&2u) | ((wv>>14)&4u) | ((wv>>21)&8u)) << (4*j);
    }
  } else {
    const i32x4* m32 = (const i32x4*)maskp + (size_t)idx*8;
    #pragma unroll
    for (int j=0;j<8;++j){
      i32x4 v = m32[j];
      out |= (unsigned)((v[0]&1) | ((v[1]&1)<<1) | ((v[2]&1)<<2) | ((v[3]&1)<<3)) << (4*j);
    }
  }
  mbits[idx] = out;
}

// ---------------- f32 -> bf16 pre-convert for q,k,v ----------------
__global__ __launch_bounds__(256) void k_cvt(const float* __restrict__ q, const float* __restrict__ k,
                                             const float* __restrict__ v,
                                             u16* __restrict__ qc, u16* __restrict__ kc, u16* __restrict__ vc){
  const float* in = blockIdx.y==0 ? q : blockIdx.y==1 ? k : v;
  u16* out = blockIdx.y==0 ? qc : blockIdx.y==1 ? kc : vc;
  const size_t i = ((size_t)blockIdx.x*256 + threadIdx.x)*8;
  float4 lo = *(const float4*)&in[i];
  float4 hi = *(const float4*)&in[i+4];
  ushort4 a, b;
  a.x=f2bf(lo.x); a.y=f2bf(lo.y); a.z=f2bf(lo.z); a.w=f2bf(lo.w);
  b.x=f2bf(hi.x); b.y=f2bf(hi.y); b.z=f2bf(hi.z); b.w=f2bf(hi.w);
  *(ushort4*)&out[i] = a;
  *(ushort4*)&out[i+4] = b;
}

// ---------------- weight transpose + bf16 convert: W[in][out] -> Wt[out][in] ----------------
__global__ __launch_bounds__(256) void k_transpose(const float* __restrict__ Wq, const float* __restrict__ Wk,
                                                   const float* __restrict__ Wv, const float* __restrict__ Wo,
                                                   u16* __restrict__ wt){
  const float* src = blockIdx.z==0 ? Wq : blockIdx.z==1 ? Wk : blockIdx.z==2 ? Wv : Wo;
  u16* dst = wt + (size_t)blockIdx.z * CH * CH;
  __shared__ float t[32][33];
  const int x = blockIdx.x*32, y = blockIdx.y*32;
  const int tx = threadIdx.x & 31, ty = threadIdx.x >> 5;
  #pragma unroll
  for (int j=0;j<32;j+=8) t[ty+j][tx] = src[(size_t)(y+ty+j)*CH + x + tx];
  __syncthreads();
  #pragma unroll
  for (int j=0;j<32;j+=8) dst[(size_t)(x+ty+j)*CH + y + tx] = f2bf(t[tx][ty+j]);
}

// ---------------- 128x128 tile, 8-wave, BK=64, global_load_lds GEMM core (m97 structure) ----------------
// A [M][CH] bf16 row-major, Bt [N-range][CH] bf16 row-major. acc[2][4] of 16x16 frags per wave.
__device__ __forceinline__ void gemm128_core(const u16* __restrict__ A, const u16* __restrict__ Bt,
                                             int m0, int n0, f32x4 acc[2][4]){
  __shared__ u16 As[128*64];
  __shared__ u16 Bs[128*64];
  const int tid = threadIdx.x, lane = tid & 63, w = tid >> 6;
  const int wm = w >> 1, wn = w & 1;
  const int lr = lane & 15, lg = lane >> 4;
  for (int k0 = 0; k0 < CH; k0 += 64){
    #pragma unroll
    for (int r=0;r<2;++r){
      const int chunk = r*512 + tid;               // 1024 chunks of 16B per tile
      const int row = chunk >> 3, ch = chunk & 7;  // row 0..127, chunk-col 0..7
      __builtin_amdgcn_global_load_lds(
        (const __attribute__((address_space(1))) void*)&A[(size_t)(m0+row)*CH + k0 + ch*8],
        (__attribute__((address_space(3))) void*)&As[(r*512 + w*64)*8], 16, 0, 0);
      __builtin_amdgcn_global_load_lds(
        (const __attribute__((address_space(1))) void*)&Bt[(size_t)(n0+row)*CH + k0 + ch*8],
        (__attribute__((address_space(3))) void*)&Bs[(r*512 + w*64)*8], 16, 0, 0);
    }
    __syncthreads();   // drains vmcnt (compiler-inserted) -> LDS tiles ready
    #pragma unroll
    for (int kk=0; kk<2; ++kk){
      bf16x8 a0 = *(const bf16x8*)&As[(wm*32      + lr)*64 + (kk*4+lg)*8];
      bf16x8 a1 = *(const bf16x8*)&As[(wm*32 + 16 + lr)*64 + (kk*4+lg)*8];
      #pragma unroll
      for (int fj=0;fj<4;++fj){
        bf16x8 b = *(const bf16x8*)&Bs[(wn*64 + fj*16 + lr)*64 + (kk*4+lg)*8];
        acc[0][fj] = __builtin_amdgcn_mfma_f32_16x16x32_bf16(a0, b, acc[0][fj], 0,0,0);
        acc[1][fj] = __builtin_amdgcn_mfma_f32_16x16x32_bf16(a1, b, acc[1][fj], 0,0,0);
      }
    }
    __syncthreads();
  }
}

// fused QKV projections: blockIdx.x>>3 selects z (q/k/v); per-z A and Wt; scatter epilogues.
__global__ __launch_bounds__(512) void k_gemm_qkv3(const u16* __restrict__ qc, const u16* __restrict__ kc,
                                                   const u16* __restrict__ vc, const u16* __restrict__ wt,
                                                   const float* __restrict__ bq, const float* __restrict__ bk,
                                                   const float* __restrict__ bv,
                                                   u16* __restrict__ qh, u16* __restrict__ kh, u16* __restrict__ vt){
  const int z = blockIdx.x >> 3;
  const int n0 = (blockIdx.x & 7) * 128;
  const int m0 = blockIdx.y * 128;
  const u16* A  = z==0 ? qc : z==1 ? kc : vc;
  const u16* Bt = wt + (size_t)z*CH*CH;
  const float* bias = z==0 ? bq : z==1 ? bk : bv;
  const float scale = z==0 ? 0.03125f : 1.0f;
  u16* qk_dst = z==0 ? qh : kh;
  f32x4 acc[2][4] = {};
  gemm128_core(A, Bt, m0, n0, acc);
  const int lane = threadIdx.x & 63, w = threadIdx.x >> 6;
  const int wm = w >> 1, wn = w & 1;
  const int lr = lane & 15, lg = lane >> 4;
  #pragma unroll
  for (int fi=0;fi<2;++fi)
  #pragma unroll
  for (int fj=0;fj<4;++fj)
  #pragma unroll
  for (int r=0;r<4;++r){
    int row = m0 + wm*32 + fi*16 + lg*4 + r;   // C/D: col=lane&15, row=(lane>>4)*4+reg
    int col = n0 + wn*64 + fj*16 + lr;
    float val = (acc[fi][fj][r] + bias[col]) * scale;
    int bb = row >> 11, ll = row & 2047, hh = col >> 6, dd = col & 63;
    if (z < 2) qk_dst[(((size_t)(bb*NH+hh)*QL + ll) << 6) + dd] = f2bf(val);
    else       vt[(((size_t)(bb*NH+hh) << 6) + dd)*KL + ll] = f2h(val);
  }
}

__global__ __launch_bounds__(512) void k_gemm_out3(const u16* __restrict__ ao, const u16* __restrict__ wto,
                                                   const float* __restrict__ bo, float* __restrict__ out){
  const int n0 = blockIdx.x * 128, m0 = blockIdx.y * 128;
  f32x4 acc[2][4] = {};
  gemm128_core(ao, wto, m0, n0, acc);
  const int lane = threadIdx.x & 63, w = threadIdx.x >> 6;
  const int wm = w >> 1, wn = w & 1;
  const int lr = lane & 15, lg = lane >> 4;
  #pragma unroll
  for (int fi=0;fi<2;++fi)
  #pragma unroll
  for (int fj=0;fj<4;++fj)
  #pragma unroll
  for (int r=0;r<4;++r){
    int row = m0 + wm*32 + fi*16 + lg*4 + r;
    int col = n0 + wn*64 + fj*16 + lr;
    out[(size_t)row*CH + col] = acc[fi][fj][r] + bo[col];
  }
}

// ---------------- legacy projection GEMMs (fallback when ws too small for bf16 copies) ----------------
__global__ __launch_bounds__(256) void k_gemm_qkv(const float* __restrict__ q, const float* __restrict__ k,
                                                  const float* __restrict__ v, const u16* __restrict__ wt,
                                                  const float* __restrict__ bq, const float* __restrict__ bk,
                                                  const float* __restrict__ bv,
                                                  u16* __restrict__ qh, u16* __restrict__ kh, u16* __restrict__ vt){
  const int z = blockIdx.z;
  const float* A = z==0 ? q : z==1 ? k : v;
  const u16* Bt = wt + (size_t)z*CH*CH;
  const float* bias = z==0 ? bq : z==1 ? bk : bv;
  u16* Cp = z==0 ? qh : z==1 ? kh : vt;
  const float scale = (z==0) ? 0.03125f : 1.0f;
  __shared__ u16 As[64][72];
  __shared__ u16 Bs[64][72];
  const int m0 = blockIdx.y*64, n0 = blockIdx.x*64;
  const int tid = threadIdx.x, lane = tid & 63, w = tid >> 6;
  const int wm = w >> 1, wn = w & 1;
  const int lr = lane & 15, lg = lane >> 4;
  f32x4 acc[2][2] = {};
  for (int k0 = 0; k0 < CH; k0 += 64){
    #pragma unroll
    for (int j=0;j<4;++j){
      int idx = tid + 256*j, r = idx >> 4, c = (idx & 15)*4;
      float4 vv = *(const float4*)&A[(size_t)(m0+r)*CH + k0 + c];
      ushort4 s; s.x=f2bf(vv.x); s.y=f2bf(vv.y); s.z=f2bf(vv.z); s.w=f2bf(vv.w);
      *(ushort4*)&As[r][c] = s;
    }
    #pragma unroll
    for (int j=0;j<2;++j){
      int idx = tid + 256*j, r = idx >> 3, c = (idx & 7)*8;
      *(uint4*)&Bs[r][c] = *(const uint4*)&Bt[(size_t)(n0+r)*CH + k0 + c];
    }
    __syncthreads();
    #pragma unroll
    for (int kk=0; kk<2; ++kk){
      bf16x8 a0 = *(const bf16x8*)&As[wm*32      + lr][kk*32 + lg*8];
      bf16x8 a1 = *(const bf16x8*)&As[wm*32 + 16 + lr][kk*32 + lg*8];
      bf16x8 b0 = *(const bf16x8*)&Bs[wn*32      + lr][kk*32 + lg*8];
      bf16x8 b1 = *(const bf16x8*)&Bs[wn*32 + 16 + lr][kk*32 + lg*8];
      acc[0][0] = __builtin_amdgcn_mfma_f32_16x16x32_bf16(a0,b0,acc[0][0],0,0,0);
      acc[0][1] = __builtin_amdgcn_mfma_f32_16x16x32_bf16(a0,b1,acc[0][1],0,0,0);
      acc[1][0] = __builtin_amdgcn_mfma_f32_16x16x32_bf16(a1,b0,acc[1][0],0,0,0);
      acc[1][1] = __builtin_amdgcn_mfma_f32_16x16x32_bf16(a1,b1,acc[1][1],0,0,0);
    }
    __syncthreads();
  }
  #pragma unroll
  for (int fi=0;fi<2;++fi)
  #pragma unroll
  for (int fj=0;fj<2;++fj)
  #pragma unroll
  for (int r=0;r<4;++r){
    int row = m0 + wm*32 + fi*16 + lg*4 + r;
    int col = n0 + wn*32 + fj*16 + lr;
    float val = (acc[fi][fj][r] + bias[col]) * scale;
    int bb = row >> 11, ll = row & 2047, hh = col >> 6, dd = col & 63;
    if (z < 2) Cp[(((size_t)(bb*NH+hh)*QL + ll) << 6) + dd] = f2bf(val);
    else       Cp[(((size_t)(bb*NH+hh) << 6) + dd)*KL + ll] = f2h(val);
  }
}

__global__ __launch_bounds__(256) void k_gemm_out(const u16* __restrict__ Ap, const u16* __restrict__ Bt,
                                                  const float* __restrict__ bias, float* __restrict__ Cp){
  __shared__ u16 As[64][72];
  __shared__ u16 Bs[64][72];
  const int m0 = blockIdx.y*64, n0 = blockIdx.x*64;
  const int tid = threadIdx.x, lane = tid & 63, w = tid >> 6;
  const int wm = w >> 1, wn = w & 1;
  const int lr = lane & 15, lg = lane >> 4;
  f32x4 acc[2][2] = {};
  for (int k0 = 0; k0 < CH; k0 += 64){
    #pragma unroll
    for (int j=0;j<2;++j){
      int idx = tid + 256*j, r = idx >> 3, c = (idx & 7)*8;
      *(uint4*)&As[r][c] = *(const uint4*)&Ap[(size_t)(m0+r)*CH + k0 + c];
      *(uint4*)&Bs[r][c] = *(const uint4*)&Bt[(size_t)(n0+r)*CH + k0 + c];
    }
    __syncthreads();
    #pragma unroll
    for (int kk=0; kk<2; ++kk){
      bf16x8 a0 = *(const bf16x8*)&As[wm*32      + lr][kk*32 + lg*8];
      bf16x8 a1 = *(const bf16x8*)&As[wm*32 + 16 + lr][kk*32 + lg*8];
      bf16x8 b0 = *(const bf16x8*)&Bs[wn*32      + lr][kk*32 + lg*8];
      bf16x8 b1 = *(const bf16x8*)&Bs[wn*32 + 16 + lr][kk*32 + lg*8];
      acc[0][0] = __builtin_amdgcn_mfma_f32_16x16x32_bf16(a0,b0,acc[0][0],0,0,0);
      acc[0][1] = __builtin_amdgcn_mfma_f32_16x16x32_bf16(a0,b1,acc[0][1],0,0,0);
      acc[1][0] = __builtin_amdgcn_mfma_f32_16x16x32_bf16(a1,b0,acc[1][0],0,0,0);
      acc[1][1] = __builtin_amdgcn_mfma_f32_16x16x32_bf16(a1,b1,acc[1][1],0,0,0);
    }
    __syncthreads();
  }
  #pragma unroll
  for (int fi=0;fi<2;++fi)
  #pragma unroll
  for (int fj=0;fj<2;++fj)
  #pragma unroll
  for (int r=0;r<4;++r){
    int row = m0 + wm*32 + fi*16 + lg*4 + r;
    int col = n0 + wn*32 + fj*16 + lr;
    Cp[(size_t)row*CH + col] = acc[fi][fj][r] + bias[col];
  }
}

// ---------------- fused attention (round-9 structure: best measured, clean writes) ----------------
template<int BITS>
__global__ __launch_bounds__(1024, 1) void k_attn(const u16* __restrict__ qh, const u16* __restrict__ kh,
                                              const _Float16* __restrict__ vt, const float* __restrict__ bias,
                                              const void* __restrict__ maskp, const int* __restrict__ flag,
                                              const unsigned* __restrict__ mbits,
                                              float* __restrict__ attn, u16* __restrict__ ao){
  __shared__ _Float16 Sh[16][SH_STRIDE];
  __shared__ float osum[8][16][17];
  __shared__ float wsum[16][16];
  __shared__ float inv_l[16];
  const int qt = BITS ? blockIdx.x : blockIdx.y;
  const int h  = BITS ? blockIdx.y : blockIdx.x;
  const int b  = blockIdx.z;
  const int q0 = qt*16, bh = b*NH + h;
  const int tid = threadIdx.x, lane = tid & 63, w = tid >> 6;
  const int lr = lane & 15, lg = lane >> 4;
  const u16* qb = qh + ((size_t)bh*QL + q0)*HD;
  const bf16x8 qf0 = *(const bf16x8*)&qb[lr*HD +      lg*8];
  const bf16x8 qf1 = *(const bf16x8*)&qb[lr*HD + 32 + lg*8];
  const float* bb = bias + ((size_t)bh*QL + q0)*KL;
  const u16* khb = kh + (size_t)bh*KL*HD;
  const _Float16* vtb = vt + (size_t)bh*HD*KL;
  const int c0 = w*128;

  f32x4 bi[8];
  unsigned mwd[8];
  #pragma unroll
  for (int ct=0; ct<8; ++ct){
    const int cb = c0 + ct*16 + lg*4;
    bi[ct] = *(const f32x4*)&bb[(size_t)lr*KL + cb];
    if (BITS) mwd[ct] = mbits[((size_t)b*QL + q0 + lr)*(KL/32) + (cb>>5)];
  }
  const int isbool = BITS ? 0 : *flag;
  const unsigned char* mb8 = (const unsigned char*)maskp + ((size_t)b*QL + q0)*KL;
  const int* mb32 = (const int*)maskp + ((size_t)b*QL + q0)*KL;

  float ps = 0.f;
  #pragma unroll
  for (int ct=0; ct<8; ++ct){
    const int cb = c0 + ct*16 + lg*4;
    f32x4 acc = bi[ct];
    const int kcol = c0 + ct*16 + lr;
    bf16x8 kf0 = *(const bf16x8*)&khb[(size_t)kcol*HD +      lg*8];
    bf16x8 kf1 = *(const bf16x8*)&khb[(size_t)kcol*HD + 32 + lg*8];
    acc = __builtin_amdgcn_mfma_f32_16x16x32_bf16(kf0, qf0, acc, 0,0,0);   // swapped: D = S^T frag
    acc = __builtin_amdgcn_mfma_f32_16x16x32_bf16(kf1, qf1, acc, 0,0,0);
    unsigned msel;
    i32x4 mv;
    if (BITS){
      msel = (mwd[ct] >> (cb & 31)) & 0xFu;
    } else if (isbool){
      unsigned mw = *(const unsigned*)&mb8[(size_t)lr*KL + cb];
      msel = (mw&1u) | ((mw>>7)&2u) | ((mw>>14)&4u) | ((mw>>21)&8u);
    } else {
      mv = *(const i32x4*)&mb32[(size_t)lr*KL + cb];
      msel = (unsigned)((mv[0]&1) | ((mv[1]&1)<<1) | ((mv[2]&1)<<2) | ((mv[3]&1)<<3));
    }
    f16x4 sv;
    #pragma unroll
    for (int r=0;r<4;++r){
      float e = ((msel >> r) & 1u) ? 0.f : __expf(acc[r]);   // bounded logits: no max-sub
      sv[r] = (_Float16)e;
      ps += e;
    }
    *(f16x4*)&Sh[lr][cb] = sv;
  }
  ps += __shfl_xor(ps, 16);
  ps += __shfl_xor(ps, 32);
  if (lane < 16) wsum[w][lr] = ps;
  __syncthreads();
  if (tid < 16){
    float s = 0.f;
    #pragma unroll
    for (int ww=0; ww<16; ++ww) s += wsum[ww][tid];
    inv_l[tid] = 1.f / s;
  }
  __syncthreads();

  if (w < 8){
    const int d0 = (w & 3)*16, kb0 = (w >> 2)*1024;
    f32x4 oacc = {};
    #pragma unroll
    for (int kb=0; kb<4; ++kb){
      f16x8 vf[8];
      #pragma unroll
      for (int i=0;i<8;++i)
        vf[i] = *(const f16x8*)&vtb[(size_t)(d0+lr)*KL + kb0 + kb*256 + i*32 + lg*8];
      #pragma unroll
      for (int i=0;i<8;++i){
        f16x8 a = *(const f16x8*)&Sh[lr][kb0 + kb*256 + i*32 + lg*8];
        oacc = __builtin_amdgcn_mfma_f32_16x16x32_f16(a, vf[i], oacc, 0,0,0);
      }
    }
    #pragma unroll
    for (int r=0;r<4;++r) osum[w][lg*4+r][lr] = oacc[r];
  } else {
    float* ob = attn + ((size_t)bh*QL + q0)*KL;
    const int r0 = (w - 8)*2;
    #pragma unroll
    for (int rr=0; rr<2; ++rr){
      const int row = r0 + rr;
      const float ivr = inv_l[row];
      #pragma unroll
      for (int ch=0; ch<8; ++ch){
        f16x4 hv = *(const f16x4*)&Sh[row][ch*256 + lane*4];
        f32x4 v;
        v[0]=(float)hv[0]*ivr; v[1]=(float)hv[1]*ivr; v[2]=(float)hv[2]*ivr; v[3]=(float)hv[3]*ivr;
        *(f32x4*)&ob[(size_t)row*KL + ch*256 + lane*4] = v;
      }
    }
  }
  __syncthreads();
  {
    const int row = tid >> 6, d = tid & 63;
    float o = (osum[d >> 4][row][d & 15] + osum[4 + (d >> 4)][row][d & 15]) * inv_l[row];
    ao[((size_t)b*QL + q0 + row)*CH + h*HD + d] = f2bf(o);
  }
}

extern "C" void kernel_launch(void* const* d_in, const int* in_sizes, int n_in,
                              void* d_out, int out_size, void* d_ws, size_t ws_size,
                              hipStream_t stream){
  const float* q    = (const float*)d_in[0];
  const float* k    = (const float*)d_in[1];
  const float* v    = (const float*)d_in[2];
  const void*  mask = d_in[3];
  const float* bias = (const float*)d_in[4];
  const float* Wq   = (const float*)d_in[5];
  const float* bq   = (const float*)d_in[6];
  const float* Wk   = (const float*)d_in[7];
  const float* bk   = (const float*)d_in[8];
  const float* Wv   = (const float*)d_in[9];
  const float* bv   = (const float*)d_in[10];
  const float* Wo   = (const float*)d_in[11];
  const float* bo   = (const float*)d_in[12];

  char* wsb = (char*)d_ws;
  int* flag = (int*)wsb;
  u16* qh = (u16*)(wsb + 256);
  u16* kh = (u16*)(wsb + 256 + 1*8388608);
  u16* vt = (u16*)(wsb + 256 + 2*8388608);
  u16* ao = (u16*)(wsb + 256 + 3*8388608);
  u16* wt = (u16*)(wsb + 256 + 4*8388608);
  unsigned* mbits = (unsigned*)(wsb + 256 + 5*8388608);
  u16* qc = (u16*)(wsb + 256 + 5*8388608 + 1048576);
  u16* kc = qc + (size_t)NB*QL*CH;
  u16* vc = kc + (size_t)NB*QL*CH;
  const size_t need_bits = 256 + 5ull*8388608 + 1048576;
  const size_t need_conv = need_bits + 3ull*NB*QL*CH*2;
  const bool usebits = (ws_size >= need_bits);
  const bool useconv = (ws_size >= need_conv);

  float* out  = (float*)d_out;
  float* attn = out + (size_t)NB*QL*CH;

  k_detect<<<1, 256, 0, stream>>>((const unsigned int*)mask, flag);
  if (usebits)
    k_maskpack<<<dim3(1024), 256, 0, stream>>>(mask, flag, mbits);
  k_transpose<<<dim3(32,32,4), 256, 0, stream>>>(Wq, Wk, Wv, Wo, wt);
  if (useconv){
    k_cvt<<<dim3(2048,3), 256, 0, stream>>>(q, k, v, qc, kc, vc);
    k_gemm_qkv3<<<dim3(24,32), 512, 0, stream>>>(qc, kc, vc, wt, bq, bk, bv, qh, kh, vt);
  } else {
    k_gemm_qkv<<<dim3(16,64,3), 256, 0, stream>>>(q, k, v, wt, bq, bk, bv, qh, kh, vt);
  }
  if (usebits)
    k_attn<1><<<dim3(128,16,2), 1024, 0, stream>>>(qh, kh, (const _Float16*)vt, bias, mask, flag, mbits, attn, ao);
  else
    k_attn<0><<<dim3(16,128,2), 1024, 0, stream>>>(qh, kh, (const _Float16*)vt, bias, mask, flag, mbits, attn, ao);
  if (useconv)
    k_gemm_out3<<<dim3(8,32), 512, 0, stream>>>(ao, wt + 3145728, bo, out);
  else
    k_gemm_out<<<dim3(16,64), 256, 0, stream>>>(ao, wt + 3145728, bo, out);
}

// Round 17
// 539.952 us; speedup vs baseline: 1.4186x; 1.0274x over previous
//
#include <hip/hip_runtime.h>
#include <hip/hip_bf16.h>

// MultiHeadAttention fused pipeline for MI355X (gfx950).
// Outputs: [0] out (2*2048*1024 f32), [1] attn (2*16*2048*2048 f32), concatenated in d_out.
// ws layout: [flag:256B][qh 8MB][kh 8MB][vt 8MB][ao 8MB][wt 8MB][mbits 1MB][qc 8][kc 8][vc 8] = ~66MB.

typedef __attribute__((ext_vector_type(8))) short bf16x8;
typedef __attribute__((ext_vector_type(8))) _Float16 f16x8;
typedef __attribute__((ext_vector_type(4))) float f32x4;
typedef __attribute__((ext_vector_type(4))) int i32x4;
typedef __attribute__((ext_vector_type(4))) _Float16 f16x4;
typedef unsigned short u16;

#define NB 2
#define QL 2048
#define KL 2048
#define CH 1024
#define NH 16
#define HD 64
#define SH_STRIDE 2600    // 16-row fallback attn stride
#define S32_STRIDE 2344   // 32-row attn stride: row 4688B (16B-aligned), 1172dw%32=20 (same spread as 2600)

__device__ __forceinline__ u16 f2bf(float f){
  unsigned u = __float_as_uint(f);
  u += 0x7fffu + ((u >> 16) & 1u);   // RNE
  return (u16)(u >> 16);
}
__device__ __forceinline__ u16 f2h(float f){
  _Float16 h = (_Float16)f;
  return *(u16*)&h;
}

// ---------------- mask dtype detector: int32 0/1 vs packed bool bytes ----------------
__global__ void k_detect(const unsigned int* __restrict__ m, int* __restrict__ flag){
  unsigned v = m[threadIdx.x];
  unsigned long long b = __ballot(v > 1u);
  __shared__ int r[4];
  if ((threadIdx.x & 63) == 0) r[threadIdx.x >> 6] = (b != 0ULL);
  __syncthreads();
  if (threadIdx.x == 0) *flag = (r[0] | r[1] | r[2] | r[3]);
}

// ---------------- mask -> 1 bit/elem (1MB; L2/L3-resident) ----------------
__global__ __launch_bounds__(256) void k_maskpack(const void* __restrict__ maskp, const int* __restrict__ flag,
                                                  unsigned* __restrict__ mbits){
  const int idx = blockIdx.x*256 + threadIdx.x;
  unsigned out = 0;
  if (*flag){
    const unsigned* m8 = (const unsigned*)maskp + (size_t)idx*8;
    #pragma unroll
    for (int j=0;j<8;++j){
      unsigned wv = m8[j];
      out |= ((wv & 1u) | ((wv>>7)&2u) | ((wv>>14)&4u) | ((wv>>21)&8u)) << (4*j);
    }
  } else {
    const i32x4* m32 = (const i32x4*)maskp + (size_t)idx*8;
    #pragma unroll
    for (int j=0;j<8;++j){
      i32x4 v = m32[j];
      out |= (unsigned)((v[0]&1) | ((v[1]&1)<<1) | ((v[2]&1)<<2) | ((v[3]&1)<<3)) << (4*j);
    }
  }
  mbits[idx] = out;
}

// ---------------- f32 -> bf16 pre-convert for q,k,v ----------------
__global__ __launch_bounds__(256) void k_cvt(const float* __restrict__ q, const float* __restrict__ k,
                                             const float* __restrict__ v,
                                             u16* __restrict__ qc, u16* __restrict__ kc, u16* __restrict__ vc){
  const float* in = blockIdx.y==0 ? q : blockIdx.y==1 ? k : v;
  u16* out = blockIdx.y==0 ? qc : blockIdx.y==1 ? kc : vc;
  const size_t i = ((size_t)blockIdx.x*256 + threadIdx.x)*8;
  float4 lo = *(const float4*)&in[i];
  float4 hi = *(const float4*)&in[i+4];
  ushort4 a, b;
  a.x=f2bf(lo.x); a.y=f2bf(lo.y); a.z=f2bf(lo.z); a.w=f2bf(lo.w);
  b.x=f2bf(hi.x); b.y=f2bf(hi.y); b.z=f2bf(hi.z); b.w=f2bf(hi.w);
  *(ushort4*)&out[i] = a;
  *(ushort4*)&out[i+4] = b;
}

// ---------------- weight transpose + bf16 convert: W[in][out] -> Wt[out][in] ----------------
__global__ __launch_bounds__(256) void k_transpose(const float* __restrict__ Wq, const float* __restrict__ Wk,
                                                   const float* __restrict__ Wv, const float* __restrict__ Wo,
                                                   u16* __restrict__ wt){
  const float* src = blockIdx.z==0 ? Wq : blockIdx.z==1 ? Wk : blockIdx.z==2 ? Wv : Wo;
  u16* dst = wt + (size_t)blockIdx.z * CH * CH;
  __shared__ float t[32][33];
  const int x = blockIdx.x*32, y = blockIdx.y*32;
  const int tx = threadIdx.x & 31, ty = threadIdx.x >> 5;
  #pragma unroll
  for (int j=0;j<32;j+=8) t[ty+j][tx] = src[(size_t)(y+ty+j)*CH + x + tx];
  __syncthreads();
  #pragma unroll
  for (int j=0;j<32;j+=8) dst[(size_t)(x+ty+j)*CH + y + tx] = f2bf(t[tx][ty+j]);
}

// ---------------- 128x128 tile, 8-wave, BK=64, global_load_lds GEMM core (m97 structure) ----------------
__device__ __forceinline__ void gemm128_core(const u16* __restrict__ A, const u16* __restrict__ Bt,
                                             int m0, int n0, f32x4 acc[2][4]){
  __shared__ u16 As[128*64];
  __shared__ u16 Bs[128*64];
  const int tid = threadIdx.x, lane = tid & 63, w = tid >> 6;
  const int wm = w >> 1, wn = w & 1;
  const int lr = lane & 15, lg = lane >> 4;
  for (int k0 = 0; k0 < CH; k0 += 64){
    #pragma unroll
    for (int r=0;r<2;++r){
      const int chunk = r*512 + tid;
      const int row = chunk >> 3, ch = chunk & 7;
      __builtin_amdgcn_global_load_lds(
        (const __attribute__((address_space(1))) void*)&A[(size_t)(m0+row)*CH + k0 + ch*8],
        (__attribute__((address_space(3))) void*)&As[(r*512 + w*64)*8], 16, 0, 0);
      __builtin_amdgcn_global_load_lds(
        (const __attribute__((address_space(1))) void*)&Bt[(size_t)(n0+row)*CH + k0 + ch*8],
        (__attribute__((address_space(3))) void*)&Bs[(r*512 + w*64)*8], 16, 0, 0);
    }
    __syncthreads();
    #pragma unroll
    for (int kk=0; kk<2; ++kk){
      bf16x8 a0 = *(const bf16x8*)&As[(wm*32      + lr)*64 + (kk*4+lg)*8];
      bf16x8 a1 = *(const bf16x8*)&As[(wm*32 + 16 + lr)*64 + (kk*4+lg)*8];
      #pragma unroll
      for (int fj=0;fj<4;++fj){
        bf16x8 b = *(const bf16x8*)&Bs[(wn*64 + fj*16 + lr)*64 + (kk*4+lg)*8];
        acc[0][fj] = __builtin_amdgcn_mfma_f32_16x16x32_bf16(a0, b, acc[0][fj], 0,0,0);
        acc[1][fj] = __builtin_amdgcn_mfma_f32_16x16x32_bf16(a1, b, acc[1][fj], 0,0,0);
      }
    }
    __syncthreads();
  }
}

__global__ __launch_bounds__(512) void k_gemm_qkv3(const u16* __restrict__ qc, const u16* __restrict__ kc,
                                                   const u16* __restrict__ vc, const u16* __restrict__ wt,
                                                   const float* __restrict__ bq, const float* __restrict__ bk,
                                                   const float* __restrict__ bv,
                                                   u16* __restrict__ qh, u16* __restrict__ kh, u16* __restrict__ vt){
  const int z = blockIdx.x >> 3;
  const int n0 = (blockIdx.x & 7) * 128;
  const int m0 = blockIdx.y * 128;
  const u16* A  = z==0 ? qc : z==1 ? kc : vc;
  const u16* Bt = wt + (size_t)z*CH*CH;
  const float* bias = z==0 ? bq : z==1 ? bk : bv;
  const float scale = z==0 ? 0.03125f : 1.0f;
  u16* qk_dst = z==0 ? qh : kh;
  f32x4 acc[2][4] = {};
  gemm128_core(A, Bt, m0, n0, acc);
  const int lane = threadIdx.x & 63, w = threadIdx.x >> 6;
  const int wm = w >> 1, wn = w & 1;
  const int lr = lane & 15, lg = lane >> 4;
  #pragma unroll
  for (int fi=0;fi<2;++fi)
  #pragma unroll
  for (int fj=0;fj<4;++fj)
  #pragma unroll
  for (int r=0;r<4;++r){
    int row = m0 + wm*32 + fi*16 + lg*4 + r;
    int col = n0 + wn*64 + fj*16 + lr;
    float val = (acc[fi][fj][r] + bias[col]) * scale;
    int bb = row >> 11, ll = row & 2047, hh = col >> 6, dd = col & 63;
    if (z < 2) qk_dst[(((size_t)(bb*NH+hh)*QL + ll) << 6) + dd] = f2bf(val);
    else       vt[(((size_t)(bb*NH+hh) << 6) + dd)*KL + ll] = f2h(val);
  }
}

__global__ __launch_bounds__(512) void k_gemm_out3(const u16* __restrict__ ao, const u16* __restrict__ wto,
                                                   const float* __restrict__ bo, float* __restrict__ out){
  const int n0 = blockIdx.x * 128, m0 = blockIdx.y * 128;
  f32x4 acc[2][4] = {};
  gemm128_core(ao, wto, m0, n0, acc);
  const int lane = threadIdx.x & 63, w = threadIdx.x >> 6;
  const int wm = w >> 1, wn = w & 1;
  const int lr = lane & 15, lg = lane >> 4;
  #pragma unroll
  for (int fi=0;fi<2;++fi)
  #pragma unroll
  for (int fj=0;fj<4;++fj)
  #pragma unroll
  for (int r=0;r<4;++r){
    int row = m0 + wm*32 + fi*16 + lg*4 + r;
    int col = n0 + wn*64 + fj*16 + lr;
    out[(size_t)row*CH + col] = acc[fi][fj][r] + bo[col];
  }
}

// ---------------- legacy projection GEMMs (fallback when ws too small for bf16 copies) ----------------
__global__ __launch_bounds__(256) void k_gemm_qkv(const float* __restrict__ q, const float* __restrict__ k,
                                                  const float* __restrict__ v, const u16* __restrict__ wt,
                                                  const float* __restrict__ bq, const float* __restrict__ bk,
                                                  const float* __restrict__ bv,
                                                  u16* __restrict__ qh, u16* __restrict__ kh, u16* __restrict__ vt){
  const int z = blockIdx.z;
  const float* A = z==0 ? q : z==1 ? k : v;
  const u16* Bt = wt + (size_t)z*CH*CH;
  const float* bias = z==0 ? bq : z==1 ? bk : bv;
  u16* Cp = z==0 ? qh : z==1 ? kh : vt;
  const float scale = (z==0) ? 0.03125f : 1.0f;
  __shared__ u16 As[64][72];
  __shared__ u16 Bs[64][72];
  const int m0 = blockIdx.y*64, n0 = blockIdx.x*64;
  const int tid = threadIdx.x, lane = tid & 63, w = tid >> 6;
  const int wm = w >> 1, wn = w & 1;
  const int lr = lane & 15, lg = lane >> 4;
  f32x4 acc[2][2] = {};
  for (int k0 = 0; k0 < CH; k0 += 64){
    #pragma unroll
    for (int j=0;j<4;++j){
      int idx = tid + 256*j, r = idx >> 4, c = (idx & 15)*4;
      float4 vv = *(const float4*)&A[(size_t)(m0+r)*CH + k0 + c];
      ushort4 s; s.x=f2bf(vv.x); s.y=f2bf(vv.y); s.z=f2bf(vv.z); s.w=f2bf(vv.w);
      *(ushort4*)&As[r][c] = s;
    }
    #pragma unroll
    for (int j=0;j<2;++j){
      int idx = tid + 256*j, r = idx >> 3, c = (idx & 7)*8;
      *(uint4*)&Bs[r][c] = *(const uint4*)&Bt[(size_t)(n0+r)*CH + k0 + c];
    }
    __syncthreads();
    #pragma unroll
    for (int kk=0; kk<2; ++kk){
      bf16x8 a0 = *(const bf16x8*)&As[wm*32      + lr][kk*32 + lg*8];
      bf16x8 a1 = *(const bf16x8*)&As[wm*32 + 16 + lr][kk*32 + lg*8];
      bf16x8 b0 = *(const bf16x8*)&Bs[wn*32      + lr][kk*32 + lg*8];
      bf16x8 b1 = *(const bf16x8*)&Bs[wn*32 + 16 + lr][kk*32 + lg*8];
      acc[0][0] = __builtin_amdgcn_mfma_f32_16x16x32_bf16(a0,b0,acc[0][0],0,0,0);
      acc[0][1] = __builtin_amdgcn_mfma_f32_16x16x32_bf16(a0,b1,acc[0][1],0,0,0);
      acc[1][0] = __builtin_amdgcn_mfma_f32_16x16x32_bf16(a1,b0,acc[1][0],0,0,0);
      acc[1][1] = __builtin_amdgcn_mfma_f32_16x16x32_bf16(a1,b1,acc[1][1],0,0,0);
    }
    __syncthreads();
  }
  #pragma unroll
  for (int fi=0;fi<2;++fi)
  #pragma unroll
  for (int fj=0;fj<2;++fj)
  #pragma unroll
  for (int r=0;r<4;++r){
    int row = m0 + wm*32 + fi*16 + lg*4 + r;
    int col = n0 + wn*32 + fj*16 + lr;
    float val = (acc[fi][fj][r] + bias[col]) * scale;
    int bb = row >> 11, ll = row & 2047, hh = col >> 6, dd = col & 63;
    if (z < 2) Cp[(((size_t)(bb*NH+hh)*QL + ll) << 6) + dd] = f2bf(val);
    else       Cp[(((size_t)(bb*NH+hh) << 6) + dd)*KL + ll] = f2h(val);
  }
}

__global__ __launch_bounds__(256) void k_gemm_out(const u16* __restrict__ Ap, const u16* __restrict__ Bt,
                                                  const float* __restrict__ bias, float* __restrict__ Cp){
  __shared__ u16 As[64][72];
  __shared__ u16 Bs[64][72];
  const int m0 = blockIdx.y*64, n0 = blockIdx.x*64;
  const int tid = threadIdx.x, lane = tid & 63, w = tid >> 6;
  const int wm = w >> 1, wn = w & 1;
  const int lr = lane & 15, lg = lane >> 4;
  f32x4 acc[2][2] = {};
  for (int k0 = 0; k0 < CH; k0 += 64){
    #pragma unroll
    for (int j=0;j<2;++j){
      int idx = tid + 256*j, r = idx >> 3, c = (idx & 7)*8;
      *(uint4*)&As[r][c] = *(const uint4*)&Ap[(size_t)(m0+r)*CH + k0 + c];
      *(uint4*)&Bs[r][c] = *(const uint4*)&Bt[(size_t)(n0+r)*CH + k0 + c];
    }
    __syncthreads();
    #pragma unroll
    for (int kk=0; kk<2; ++kk){
      bf16x8 a0 = *(const bf16x8*)&As[wm*32      + lr][kk*32 + lg*8];
      bf16x8 a1 = *(const bf16x8*)&As[wm*32 + 16 + lr][kk*32 + lg*8];
      bf16x8 b0 = *(const bf16x8*)&Bs[wn*32      + lr][kk*32 + lg*8];
      bf16x8 b1 = *(const bf16x8*)&Bs[wn*32 + 16 + lr][kk*32 + lg*8];
      acc[0][0] = __builtin_amdgcn_mfma_f32_16x16x32_bf16(a0,b0,acc[0][0],0,0,0);
      acc[0][1] = __builtin_amdgcn_mfma_f32_16x16x32_bf16(a0,b1,acc[0][1],0,0,0);
      acc[1][0] = __builtin_amdgcn_mfma_f32_16x16x32_bf16(a1,b0,acc[1][0],0,0,0);
      acc[1][1] = __builtin_amdgcn_mfma_f32_16x16x32_bf16(a1,b1,acc[1][1],0,0,0);
    }
    __syncthreads();
  }
  #pragma unroll
  for (int fi=0;fi<2;++fi)
  #pragma unroll
  for (int fj=0;fj<2;++fj)
  #pragma unroll
  for (int r=0;r<4;++r){
    int row = m0 + wm*32 + fi*16 + lg*4 + r;
    int col = n0 + wn*32 + fj*16 + lr;
    Cp[(size_t)row*CH + col] = acc[fi][fj][r] + bias[col];
  }
}

// ---------------- 32-row fused attention (R9 structure, doubled tile: 8 serial blocks/CU) ----------------
// Phase 1: wave w owns cols [w*128,+128) for both 16-row groups (sequential); swapped QK^T,
// bias C-init, mask bits, exp -> Sh[32][S32_STRIDE] f16 (150KB -> 1 block/CU).
// Phase 2: waves 0-7 PV (d-strip (w&3)*16, row-half (w>>2)*16, FULL K) -> direct ao write
// (no osum/no final barrier); waves 8-15 burst-write normalized attn (4 rows each, 1KB/instr).
__global__ __launch_bounds__(1024, 1) void k_attn32(const u16* __restrict__ qh, const u16* __restrict__ kh,
                                              const _Float16* __restrict__ vt, const float* __restrict__ bias,
                                              const unsigned* __restrict__ mbits,
                                              float* __restrict__ attn, u16* __restrict__ ao){
  __shared__ _Float16 Sh[32][S32_STRIDE];   // 150.0 KB
  __shared__ float wsum[16][32];            // 2 KB
  __shared__ float inv_l[32];
  const int qt = blockIdx.x, h = blockIdx.y, b = blockIdx.z;
  const int q0 = qt*32, bh = b*NH + h;
  const int tid = threadIdx.x, lane = tid & 63, w = tid >> 6;
  const int lr = lane & 15, lg = lane >> 4;
  const float* bb = bias + ((size_t)bh*QL + q0)*KL;
  const u16* khb = kh + (size_t)bh*KL*HD;
  const _Float16* vtb = vt + (size_t)bh*HD*KL;
  const int c0 = w*128;

  // ---- phase 1: two 16-row groups ----
  #pragma unroll
  for (int g=0; g<2; ++g){
    const int qrow = q0 + g*16;
    const u16* qb = qh + ((size_t)bh*QL + qrow)*HD;
    const bf16x8 qf0 = *(const bf16x8*)&qb[lr*HD +      lg*8];
    const bf16x8 qf1 = *(const bf16x8*)&qb[lr*HD + 32 + lg*8];
    f32x4 bi[8];
    unsigned mwd[8];
    #pragma unroll
    for (int ct=0; ct<8; ++ct){
      const int cb = c0 + ct*16 + lg*4;
      bi[ct] = *(const f32x4*)&bb[(size_t)(g*16+lr)*KL + cb];
      mwd[ct] = mbits[((size_t)b*QL + qrow + lr)*(KL/32) + (cb>>5)];
    }
    float ps = 0.f;
    #pragma unroll
    for (int ct=0; ct<8; ++ct){
      const int cb = c0 + ct*16 + lg*4;
      f32x4 acc = bi[ct];
      const int kcol = c0 + ct*16 + lr;
      bf16x8 kf0 = *(const bf16x8*)&khb[(size_t)kcol*HD +      lg*8];
      bf16x8 kf1 = *(const bf16x8*)&khb[(size_t)kcol*HD + 32 + lg*8];
      acc = __builtin_amdgcn_mfma_f32_16x16x32_bf16(kf0, qf0, acc, 0,0,0);   // swapped: D = S^T frag
      acc = __builtin_amdgcn_mfma_f32_16x16x32_bf16(kf1, qf1, acc, 0,0,0);
      const unsigned msel = (mwd[ct] >> (cb & 31)) & 0xFu;
      f16x4 sv;
      #pragma unroll
      for (int r=0;r<4;++r){
        float e = ((msel >> r) & 1u) ? 0.f : __expf(acc[r]);   // bounded logits: no max-sub
        sv[r] = (_Float16)e;
        ps += e;
      }
      *(f16x4*)&Sh[g*16+lr][cb] = sv;
    }
    ps += __shfl_xor(ps, 16);
    ps += __shfl_xor(ps, 32);
    if (lane < 16) wsum[w][g*16+lr] = ps;
  }
  __syncthreads();
  if (tid < 32){
    float s = 0.f;
    #pragma unroll
    for (int ww=0; ww<16; ++ww) s += wsum[ww][tid];
    inv_l[tid] = 1.f / s;
  }
  __syncthreads();

  if (w < 8){
    // ---- PV: d-strip (w&3)*16, row-half (w>>2)*16, full K; direct ao write ----
    const int d0 = (w & 3)*16, rh = (w >> 2)*16;
    f32x4 oacc = {};
    #pragma unroll
    for (int kb=0; kb<8; ++kb){
      f16x8 vf[8], af[8];
      #pragma unroll
      for (int i=0;i<8;++i){
        vf[i] = *(const f16x8*)&vtb[(size_t)(d0+lr)*KL + kb*256 + i*32 + lg*8];
        af[i] = *(const f16x8*)&Sh[rh+lr][kb*256 + i*32 + lg*8];
      }
      #pragma unroll
      for (int i=0;i<8;++i)
        oacc = __builtin_amdgcn_mfma_f32_16x16x32_f16(af[i], vf[i], oacc, 0,0,0);
    }
    #pragma unroll
    for (int r=0;r<4;++r){
      const int row = rh + lg*4 + r;   // D: row=(lane>>4)*4+reg (q-row), col=lane&15 (d)
      ao[((size_t)b*QL + q0 + row)*CH + h*HD + d0 + lr] = f2bf(oacc[r] * inv_l[row]);
    }
  } else {
    // ---- writers: 4 rows each, normalized f32 attn, 1KB contiguous per instruction ----
    float* ob = attn + ((size_t)bh*QL + q0)*KL;
    const int r0 = (w - 8)*4;
    #pragma unroll
    for (int rr=0; rr<4; ++rr){
      const int row = r0 + rr;
      const float ivr = inv_l[row];
      float* orow = ob + (size_t)row*KL;
      #pragma unroll
      for (int ch=0; ch<8; ++ch){
        f16x4 hv = *(const f16x4*)&Sh[row][ch*256 + lane*4];
        f32x4 v;
        v[0]=(float)hv[0]*ivr; v[1]=(float)hv[1]*ivr; v[2]=(float)hv[2]*ivr; v[3]=(float)hv[3]*ivr;
        *(f32x4*)&orow[ch*256 + lane*4] = v;
      }
    }
  }
}

// ---------------- 16-row fused attention fallback (no mbits workspace) ----------------
template<int BITS>
__global__ __launch_bounds__(1024, 1) void k_attn(const u16* __restrict__ qh, const u16* __restrict__ kh,
                                              const _Float16* __restrict__ vt, const float* __restrict__ bias,
                                              const void* __restrict__ maskp, const int* __restrict__ flag,
                                              const unsigned* __restrict__ mbits,
                                              float* __restrict__ attn, u16* __restrict__ ao){
  __shared__ _Float16 Sh[16][SH_STRIDE];
  __shared__ float osum[8][16][17];
  __shared__ float wsum[16][16];
  __shared__ float inv_l[16];
  const int qt = BITS ? blockIdx.x : blockIdx.y;
  const int h  = BITS ? blockIdx.y : blockIdx.x;
  const int b  = blockIdx.z;
  const int q0 = qt*16, bh = b*NH + h;
  const int tid = threadIdx.x, lane = tid & 63, w = tid >> 6;
  const int lr = lane & 15, lg = lane >> 4;
  const u16* qb = qh + ((size_t)bh*QL + q0)*HD;
  const bf16x8 qf0 = *(const bf16x8*)&qb[lr*HD +      lg*8];
  const bf16x8 qf1 = *(const bf16x8*)&qb[lr*HD + 32 + lg*8];
  const float* bb = bias + ((size_t)bh*QL + q0)*KL;
  const u16* khb = kh + (size_t)bh*KL*HD;
  const _Float16* vtb = vt + (size_t)bh*HD*KL;
  const int c0 = w*128;

  f32x4 bi[8];
  unsigned mwd[8];
  #pragma unroll
  for (int ct=0; ct<8; ++ct){
    const int cb = c0 + ct*16 + lg*4;
    bi[ct] = *(const f32x4*)&bb[(size_t)lr*KL + cb];
    if (BITS) mwd[ct] = mbits[((size_t)b*QL + q0 + lr)*(KL/32) + (cb>>5)];
  }
  const int isbool = BITS ? 0 : *flag;
  const unsigned char* mb8 = (const unsigned char*)maskp + ((size_t)b*QL + q0)*KL;
  const int* mb32 = (const int*)maskp + ((size_t)b*QL + q0)*KL;

  float ps = 0.f;
  #pragma unroll
  for (int ct=0; ct<8; ++ct){
    const int cb = c0 + ct*16 + lg*4;
    f32x4 acc = bi[ct];
    const int kcol = c0 + ct*16 + lr;
    bf16x8 kf0 = *(const bf16x8*)&khb[(size_t)kcol*HD +      lg*8];
    bf16x8 kf1 = *(const bf16x8*)&khb[(size_t)kcol*HD + 32 + lg*8];
    acc = __builtin_amdgcn_mfma_f32_16x16x32_bf16(kf0, qf0, acc, 0,0,0);
    acc = __builtin_amdgcn_mfma_f32_16x16x32_bf16(kf1, qf1, acc, 0,0,0);
    unsigned msel;
    i32x4 mv;
    if (BITS){
      msel = (mwd[ct] >> (cb & 31)) & 0xFu;
    } else if (isbool){
      unsigned mw = *(const unsigned*)&mb8[(size_t)lr*KL + cb];
      msel = (mw&1u) | ((mw>>7)&2u) | ((mw>>14)&4u) | ((mw>>21)&8u);
    } else {
      mv = *(const i32x4*)&mb32[(size_t)lr*KL + cb];
      msel = (unsigned)((mv[0]&1) | ((mv[1]&1)<<1) | ((mv[2]&1)<<2) | ((mv[3]&1)<<3));
    }
    f16x4 sv;
    #pragma unroll
    for (int r=0;r<4;++r){
      float e = ((msel >> r) & 1u) ? 0.f : __expf(acc[r]);
      sv[r] = (_Float16)e;
      ps += e;
    }
    *(f16x4*)&Sh[lr][cb] = sv;
  }
  ps += __shfl_xor(ps, 16);
  ps += __shfl_xor(ps, 32);
  if (lane < 16) wsum[w][lr] = ps;
  __syncthreads();
  if (tid < 16){
    float s = 0.f;
    #pragma unroll
    for (int ww=0; ww<16; ++ww) s += wsum[ww][tid];
    inv_l[tid] = 1.f / s;
  }
  __syncthreads();

  if (w < 8){
    const int d0 = (w & 3)*16, kb0 = (w >> 2)*1024;
    f32x4 oacc = {};
    #pragma unroll
    for (int kb=0; kb<4; ++kb){
      f16x8 vf[8];
      #pragma unroll
      for (int i=0;i<8;++i)
        vf[i] = *(const f16x8*)&vtb[(size_t)(d0+lr)*KL + kb0 + kb*256 + i*32 + lg*8];
      #pragma unroll
      for (int i=0;i<8;++i){
        f16x8 a = *(const f16x8*)&Sh[lr][kb0 + kb*256 + i*32 + lg*8];
        oacc = __builtin_amdgcn_mfma_f32_16x16x32_f16(a, vf[i], oacc, 0,0,0);
      }
    }
    #pragma unroll
    for (int r=0;r<4;++r) osum[w][lg*4+r][lr] = oacc[r];
  } else {
    float* ob = attn + ((size_t)bh*QL + q0)*KL;
    const int r0 = (w - 8)*2;
    #pragma unroll
    for (int rr=0; rr<2; ++rr){
      const int row = r0 + rr;
      const float ivr = inv_l[row];
      #pragma unroll
      for (int ch=0; ch<8; ++ch){
        f16x4 hv = *(const f16x4*)&Sh[row][ch*256 + lane*4];
        f32x4 v;
        v[0]=(float)hv[0]*ivr; v[1]=(float)hv[1]*ivr; v[2]=(float)hv[2]*ivr; v[3]=(float)hv[3]*ivr;
        *(f32x4*)&ob[(size_t)row*KL + ch*256 + lane*4] = v;
      }
    }
  }
  __syncthreads();
  {
    const int row = tid >> 6, d = tid & 63;
    float o = (osum[d >> 4][row][d & 15] + osum[4 + (d >> 4)][row][d & 15]) * inv_l[row];
    ao[((size_t)b*QL + q0 + row)*CH + h*HD + d] = f2bf(o);
  }
}

extern "C" void kernel_launch(void* const* d_in, const int* in_sizes, int n_in,
                              void* d_out, int out_size, void* d_ws, size_t ws_size,
                              hipStream_t stream){
  const float* q    = (const float*)d_in[0];
  const float* k    = (const float*)d_in[1];
  const float* v    = (const float*)d_in[2];
  const void*  mask = d_in[3];
  const float* bias = (const float*)d_in[4];
  const float* Wq   = (const float*)d_in[5];
  const float* bq   = (const float*)d_in[6];
  const float* Wk   = (const float*)d_in[7];
  const float* bk   = (const float*)d_in[8];
  const float* Wv   = (const float*)d_in[9];
  const float* bv   = (const float*)d_in[10];
  const float* Wo   = (const float*)d_in[11];
  const float* bo   = (const float*)d_in[12];

  char* wsb = (char*)d_ws;
  int* flag = (int*)wsb;
  u16* qh = (u16*)(wsb + 256);
  u16* kh = (u16*)(wsb + 256 + 1*8388608);
  u16* vt = (u16*)(wsb + 256 + 2*8388608);
  u16* ao = (u16*)(wsb + 256 + 3*8388608);
  u16* wt = (u16*)(wsb + 256 + 4*8388608);
  unsigned* mbits = (unsigned*)(wsb + 256 + 5*8388608);
  u16* qc = (u16*)(wsb + 256 + 5*8388608 + 1048576);
  u16* kc = qc + (size_t)NB*QL*CH;
  u16* vc = kc + (size_t)NB*QL*CH;
  const size_t need_bits = 256 + 5ull*8388608 + 1048576;
  const size_t need_conv = need_bits + 3ull*NB*QL*CH*2;
  const bool usebits = (ws_size >= need_bits);
  const bool useconv = (ws_size >= need_conv);

  float* out  = (float*)d_out;
  float* attn = out + (size_t)NB*QL*CH;

  k_detect<<<1, 256, 0, stream>>>((const unsigned int*)mask, flag);
  if (usebits)
    k_maskpack<<<dim3(1024), 256, 0, stream>>>(mask, flag, mbits);
  k_transpose<<<dim3(32,32,4), 256, 0, stream>>>(Wq, Wk, Wv, Wo, wt);
  if (useconv){
    k_cvt<<<dim3(2048,3), 256, 0, stream>>>(q, k, v, qc, kc, vc);
    k_gemm_qkv3<<<dim3(24,32), 512, 0, stream>>>(qc, kc, vc, wt, bq, bk, bv, qh, kh, vt);
  } else {
    k_gemm_qkv<<<dim3(16,64,3), 256, 0, stream>>>(q, k, v, wt, bq, bk, bv, qh, kh, vt);
  }
  if (usebits)
    k_attn32<<<dim3(64,16,2), 1024, 0, stream>>>(qh, kh, (const _Float16*)vt, bias, mbits, attn, ao);
  else
    k_attn<0><<<dim3(16,128,2), 1024, 0, stream>>>(qh, kh, (const _Float16*)vt, bias, mask, flag, mbits, attn, ao);
  if (useconv)
    k_gemm_out3<<<dim3(8,32), 512, 0, stream>>>(ao, wt + 3145728, bo, out);
  else
    k_gemm_out<<<dim3(16,64), 256, 0, stream>>>(ao, wt + 3145728, bo, out);
}